// Round 2
// baseline (419.205 us; speedup 1.0000x reference)
//
#include <hip/hip_runtime.h>
#include <stdint.h>

#define S_LEN 2048
#define NH 16
#define DM 1024
#define HD 64
#define NB 2
#define TOK (NB * S_LEN)  // 4096

typedef __attribute__((ext_vector_type(8))) short short8v;  // 8 bf16 = 4 VGPR
typedef __attribute__((ext_vector_type(4))) float f32x4;
typedef __attribute__((ext_vector_type(2))) unsigned int u32x2;
typedef unsigned short u16;
typedef unsigned int u32;

__device__ __forceinline__ float bf2f(u16 u) {
    u32 x = ((u32)u) << 16;
    return __builtin_bit_cast(float, x);
}
__device__ __forceinline__ u16 f2bf(float f) {  // RNE
    u32 u = __builtin_bit_cast(u32, f);
    return (u16)((u + 0x7FFFu + ((u >> 16) & 1u)) >> 16);
}

// async global->LDS, 16B per lane. LDS dest = wave-uniform base + lane*16 (HW).
// Generic LDS pointer = aperture(hi32) | offset(lo32): truncate to 32b offset.
__device__ __forceinline__ void gld_lds16(const void* g, void* lds_base_uniform) {
    auto gp = (const __attribute__((address_space(1))) u32*)(uintptr_t)g;
    auto lp = (__attribute__((address_space(3))) u32*)(uintptr_t)(u32)(uintptr_t)lds_base_uniform;
    __builtin_amdgcn_global_load_lds(gp, lp, 16, 0, 0);
}

// ---------------------------------------------------------------------------
// dtype sniffer: flag=1 if x is bf16, 0 if fp32. Samples low u16 of 4096 u32
// words (bf16 data -> sane exponents ~100%; fp32 data -> random mantissa ~25%).
// ---------------------------------------------------------------------------
__global__ void detect_dtype(const u32* __restrict__ xw, int* __restrict__ flag) {
    __shared__ int cnt[4];
    const int t = threadIdx.x;
    int c = 0;
#pragma unroll
    for (int j = 0; j < 16; ++j) {
        const u32 wd = xw[(t * 16 + j) * 64];  // spread over first 1MB
        const u32 e = (wd >> 7) & 0xFF;        // exponent of LOW u16 as bf16
        c += (e >= 0x58 && e <= 0x98) ? 1 : 0;
    }
#pragma unroll
    for (int off = 1; off < 64; off <<= 1) c += __shfl_xor(c, off);
    if ((t & 63) == 0) cnt[t >> 6] = c;
    __syncthreads();
    if (t == 0) flag[0] = (cnt[0] + cnt[1] + cnt[2] + cnt[3] >= 2600) ? 1 : 0;
}

// ---------------------------------------------------------------------------
// C[m,n] = sum_k A[m,k]*Bt[n,k] + bias[n]; fp32 accum. 128x128 tile, BK=32.
// Per-operand dtype: *_flagged ? (runtime flag: 1=bf16,0=fp32) : always bf16.
// ---------------------------------------------------------------------------
__global__ __launch_bounds__(256) void gemm_bt_bias(
    const void* __restrict__ Av, const void* __restrict__ Btv,
    const void* __restrict__ biasv, void* __restrict__ Cv,
    int M, int N, int K, const int* __restrict__ flagp,
    int a_flagged, int b_flagged, int out_flagged) {
    __shared__ __align__(16) u16 lA[128 * 32];
    __shared__ __align__(16) u16 lB[128 * 32];
    const int fl = flagp[0];
    const int fa = a_flagged ? fl : 1;
    const int fb = b_flagged ? fl : 1;
    const int fo = out_flagged ? fl : 1;

    const int tid = threadIdx.x;
    const int w = __builtin_amdgcn_readfirstlane(tid >> 6);
    const int lane = tid & 63;
    const int quad = lane >> 4;
    const int l16 = lane & 15;
    const int bm = blockIdx.y * 128;
    const int bn = blockIdx.x * 128;
    const int wm = (w >> 1) * 64;
    const int wn = (w & 1) * 64;

    f32x4 acc[4][4];
#pragma unroll
    for (int i = 0; i < 4; ++i)
#pragma unroll
        for (int j = 0; j < 4; ++j) acc[i][j] = {0.f, 0.f, 0.f, 0.f};

    const int kiters = K >> 5;
    for (int kk = 0; kk < kiters; ++kk) {
        __syncthreads();  // previous tile fully consumed
        if (fa) {
            const u16* A = (const u16*)Av;
#pragma unroll
            for (int c = 0; c < 2; ++c) {
                const int chunk = w * 2 + c;
                const int off = chunk * 1024 + lane * 16;  // byte off in 8KB tile
                const int m = off >> 6;
                const int kb = off & 63;
                gld_lds16((const char*)(A + (size_t)(bm + m) * K + kk * 32) + kb,
                          (char*)lA + chunk * 1024);
            }
        } else {
            const float* Af = (const float*)Av;
#pragma unroll
            for (int c = 0; c < 2; ++c) {
                const int e = (w * 2 + c) * 512 + lane * 8;  // element off in tile
                const int m = e >> 5, kc = e & 31;
                const float* ga = Af + (size_t)(bm + m) * K + kk * 32 + kc;
                const f32x4 v0 = *(const f32x4*)ga;
                const f32x4 v1 = *(const f32x4*)(ga + 4);
                short8v o;
#pragma unroll
                for (int q = 0; q < 4; ++q) o[q] = (short)f2bf(v0[q]);
#pragma unroll
                for (int q = 0; q < 4; ++q) o[4 + q] = (short)f2bf(v1[q]);
                *(short8v*)&lA[m * 32 + kc] = o;
            }
        }
        if (fb) {
            const u16* Bt = (const u16*)Btv;
#pragma unroll
            for (int c = 0; c < 2; ++c) {
                const int chunk = w * 2 + c;
                const int off = chunk * 1024 + lane * 16;
                const int m = off >> 6;
                const int kb = off & 63;
                gld_lds16((const char*)(Bt + (size_t)(bn + m) * K + kk * 32) + kb,
                          (char*)lB + chunk * 1024);
            }
        } else {
            const float* Btf = (const float*)Btv;
#pragma unroll
            for (int c = 0; c < 2; ++c) {
                const int e = (w * 2 + c) * 512 + lane * 8;
                const int m = e >> 5, kc = e & 31;
                const float* ga = Btf + (size_t)(bn + m) * K + kk * 32 + kc;
                const f32x4 v0 = *(const f32x4*)ga;
                const f32x4 v1 = *(const f32x4*)(ga + 4);
                short8v o;
#pragma unroll
                for (int q = 0; q < 4; ++q) o[q] = (short)f2bf(v0[q]);
#pragma unroll
                for (int q = 0; q < 4; ++q) o[4 + q] = (short)f2bf(v1[q]);
                *(short8v*)&lB[m * 32 + kc] = o;
            }
        }
        __syncthreads();  // drains vmcnt (async LDS loads) + lgkm + barrier

        short8v af[4], bf[4];
#pragma unroll
        for (int t = 0; t < 4; ++t) {
            af[t] = *(const short8v*)&lA[(wm + t * 16 + l16) * 32 + quad * 8];
            bf[t] = *(const short8v*)&lB[(wn + t * 16 + l16) * 32 + quad * 8];
        }
#pragma unroll
        for (int i = 0; i < 4; ++i)
#pragma unroll
            for (int j = 0; j < 4; ++j)
                acc[i][j] = __builtin_amdgcn_mfma_f32_16x16x32_bf16(af[i], bf[j], acc[i][j], 0, 0, 0);
    }

    // epilogue: C row = quad*4+r, col = lane&15 (m89/m91-verified layout)
#pragma unroll
    for (int j = 0; j < 4; ++j) {
        const int col = bn + wn + j * 16 + l16;
        const float bv = fl ? bf2f(((const u16*)biasv)[col]) : ((const float*)biasv)[col];
#pragma unroll
        for (int i = 0; i < 4; ++i) {
            const int row0 = bm + wm + i * 16 + quad * 4;
#pragma unroll
            for (int r = 0; r < 4; ++r) {
                const float val = acc[i][j][r] + bv;
                const size_t idx = (size_t)(row0 + r) * N + col;
                if (fo) ((u16*)Cv)[idx] = f2bf(val);
                else ((float*)Cv)[idx] = val;
            }
        }
    }
}

// ---------------------------------------------------------------------------
// RoPE on q,k + reorder to (B,H,S,64). One thread per rotation pair.
// ---------------------------------------------------------------------------
__global__ __launch_bounds__(256) void rope_reorder(
    const u16* __restrict__ qkv, u16* __restrict__ qws, u16* __restrict__ kws) {
    const int idx = blockIdx.x * 256 + threadIdx.x;  // B*S*H*32 = 2^21
    const int i = idx & 31;
    const int h = (idx >> 5) & 15;
    const int s = (idx >> 9) & 2047;
    const int b = idx >> 20;
    const u16* src = qkv + ((size_t)(b * S_LEN + s)) * (3 * DM) + h * HD + 2 * i;
    const u32 qp = *(const u32*)(src);
    const u32 kp = *(const u32*)(src + DM);
    const float q1 = bf2f((u16)qp), q2 = bf2f((u16)(qp >> 16));
    const float k1 = bf2f((u16)kp), k2 = bf2f((u16)(kp >> 16));
    const float freq = expf(-(float)(2 * i) * 0.14391156831212787f);  // 10000^(-2i/64)
    const float th = (float)s * freq;
    float sn, cs;
    sincosf(th, &sn, &cs);
    const float oq1 = q1 * cs - q2 * sn, oq2 = q1 * sn + q2 * cs;
    const float ok1 = k1 * cs - k2 * sn, ok2 = k1 * sn + k2 * cs;
    const size_t dst = ((size_t)((b * NH + h) * S_LEN + s)) * HD + 2 * i;
    *(u32*)(qws + dst) = (u32)f2bf(oq1) | ((u32)f2bf(oq2) << 16);
    *(u32*)(kws + dst) = (u32)f2bf(ok1) | ((u32)f2bf(ok2) << 16);
}

// ---------------------------------------------------------------------------
// V -> V^T (B,H,64,S) via padded LDS tile (PV A-operand must be K-contiguous)
// ---------------------------------------------------------------------------
__global__ __launch_bounds__(256) void v_transpose(
    const u16* __restrict__ qkv, u16* __restrict__ vT) {
    __shared__ u16 tile[64 * 65];
    const int s0 = blockIdx.x * 64;
    const int h = blockIdx.y, b = blockIdx.z;
    const int t = threadIdx.x;
#pragma unroll
    for (int it = 0; it < 16; ++it) {
        const int e = t + 256 * it;
        const int sl = e >> 6, d = e & 63;
        tile[sl * 65 + d] =
            qkv[((size_t)(b * S_LEN + s0 + sl)) * (3 * DM) + 2 * DM + h * HD + d];
    }
    __syncthreads();
#pragma unroll
    for (int it = 0; it < 16; ++it) {
        const int e = t + 256 * it;
        const int d = e >> 6, sl = e & 63;
        vT[((size_t)((b * NH + h) * HD + d)) * S_LEN + s0 + sl] = tile[sl * 65 + d];
    }
}

// ---------------------------------------------------------------------------
// Flash attention, swapped-operand + software-pipelined. Block = 4 waves;
// each wave owns ONE 16-row q-strip (block covers 64 rows) -> grid.x = S/64
// = 32 -> 1024 blocks -> 4 blocks/CU -> 4 waves/SIMD (2x TLP vs R1).
// Per kt iteration, K(kt+1)/V(kt+1) fragments are prefetched into registers
// (clamped index, no divergence) BEFORE consuming kt's registers, so global
// load latency overlaps softmax+PV of the current tile (ILP).
//
// S^T = mfma(K,Q): lane holds 8 scores of one q-row (q=l16); row max/sum =
// 7 in-lane VALU + shfl_xor(16) + shfl_xor(32). P packed to bf16 in-register,
// staged via 2x ds_write_b64 into stride-20-u32 padded rows (2-way banks,
// free), re-read as b128 B-fragment. O^T = mfma(V^T, P). Causal.
// ---------------------------------------------------------------------------
__global__ __launch_bounds__(256, 4) void attn_kernel(
    const u16* __restrict__ qws, const u16* __restrict__ kws,
    const u16* __restrict__ vT, u16* __restrict__ ows) {
    // per-wave private P staging: [wave][16 q-rows][20 u32 (16 + pad)]
    __shared__ __align__(16) u32 pl32[4][16 * 20];  // 5120 B
    const int t = threadIdx.x;
    const int w = __builtin_amdgcn_readfirstlane(t >> 6);
    const int lane = t & 63;
    const int quad = lane >> 4;
    const int l16 = lane & 15;
    const int h = blockIdx.y, b = blockIdx.z;

    const int q0 = blockIdx.x * 64 + w * 16;

    const size_t bh = (size_t)(b * NH + h);
    const u16* qb = qws + bh * (size_t)S_LEN * HD;
    const u16* kb = kws + bh * (size_t)S_LEN * HD;
    const u16* vb = vT + bh * (size_t)HD * S_LEN;

    short8v qf[2];
#pragma unroll
    for (int hf = 0; hf < 2; ++hf)
        qf[hf] = *(const short8v*)(qb + (size_t)(q0 + l16) * HD + hf * 32 + quad * 8);

    f32x4 oaccT[4];  // [d-frag]: row = d (quad*4+r), col = q (l16)
#pragma unroll
    for (int d = 0; d < 4; ++d) oaccT[d] = {0.f, 0.f, 0.f, 0.f};
    float mrow = -__builtin_inff();
    float lrow = 0.f;

    const int ktl = (q0 + 15) >> 5;
    u32* prow = &pl32[w][l16 * 20];

    // prologue: fragments for kt = 0
    short8v kf[2][2], vf[4];
#pragma unroll
    for (int sub = 0; sub < 2; ++sub)
#pragma unroll
        for (int hf = 0; hf < 2; ++hf)
            kf[sub][hf] = *(const short8v*)(kb + (size_t)(sub * 16 + l16) * HD + hf * 32 + quad * 8);
#pragma unroll
    for (int d = 0; d < 4; ++d)
        vf[d] = *(const short8v*)(vb + (size_t)(d * 16 + l16) * S_LEN + quad * 8);

    for (int kt = 0; kt <= ktl; ++kt) {
        // prefetch kt+1 fragments (clamped: last iter re-loads same tile)
        const int ktn = (kt < ktl) ? (kt + 1) : ktl;
        short8v kf_n[2][2], vf_n[4];
#pragma unroll
        for (int sub = 0; sub < 2; ++sub)
#pragma unroll
            for (int hf = 0; hf < 2; ++hf)
                kf_n[sub][hf] = *(const short8v*)(kb + (size_t)(ktn * 32 + sub * 16 + l16) * HD +
                                                 hf * 32 + quad * 8);
#pragma unroll
        for (int d = 0; d < 4; ++d)
            vf_n[d] = *(const short8v*)(vb + (size_t)(d * 16 + l16) * S_LEN + ktn * 32 + quad * 8);

        // S^T tiles: row = k (quad*4+r), col = q (l16)
        const f32x4 z = {0.f, 0.f, 0.f, 0.f};
        f32x4 s0 = __builtin_amdgcn_mfma_f32_16x16x32_bf16(kf[0][0], qf[0], z, 0, 0, 0);
        s0 = __builtin_amdgcn_mfma_f32_16x16x32_bf16(kf[0][1], qf[1], s0, 0, 0, 0);
        f32x4 s1 = __builtin_amdgcn_mfma_f32_16x16x32_bf16(kf[1][0], qf[0], z, 0, 0, 0);
        s1 = __builtin_amdgcn_mfma_f32_16x16x32_bf16(kf[1][1], qf[1], s1, 0, 0, 0);

        const int qg = q0 + l16;
        float sv[8];
#pragma unroll
        for (int r = 0; r < 4; ++r) {
            sv[r] = s0[r] * 0.125f;
            sv[4 + r] = s1[r] * 0.125f;
        }
        if (kt == ktl) {  // diagonal tile: mask k > q (wave-uniform branch)
            const int kbase = kt * 32 + quad * 4;
#pragma unroll
            for (int r = 0; r < 4; ++r) {
                if (kbase + r > qg) sv[r] = -__builtin_inff();
                if (kbase + 16 + r > qg) sv[4 + r] = -__builtin_inff();
            }
        }
        // row (per-q) max: 7 in-lane + 2 cross-lane
        float mx = fmaxf(sv[0], sv[1]);
        mx = fmaxf(mx, fmaxf(sv[2], sv[3]));
        mx = fmaxf(mx, fmaxf(sv[4], sv[5]));
        mx = fmaxf(mx, fmaxf(sv[6], sv[7]));
        mx = fmaxf(mx, __shfl_xor(mx, 16));
        mx = fmaxf(mx, __shfl_xor(mx, 32));
        const float mnew = fmaxf(mrow, mx);
        const float alpha = __expf(mrow - mnew);
        mrow = mnew;
        float p[8], ps = 0.f;
#pragma unroll
        for (int j = 0; j < 8; ++j) {
            p[j] = __expf(sv[j] - mnew);
            ps += p[j];
        }
        ps += __shfl_xor(ps, 16);
        ps += __shfl_xor(ps, 32);
        lrow = lrow * alpha + ps;
#pragma unroll
        for (int d = 0; d < 4; ++d) oaccT[d] *= alpha;
        // pack P[q=l16][k] to bf16 pairs; 2x b64 writes
        u32x2 lo, hi;
        lo.x = (u32)f2bf(p[0]) | ((u32)f2bf(p[1]) << 16);
        lo.y = (u32)f2bf(p[2]) | ((u32)f2bf(p[3]) << 16);
        hi.x = (u32)f2bf(p[4]) | ((u32)f2bf(p[5]) << 16);
        hi.y = (u32)f2bf(p[6]) | ((u32)f2bf(p[7]) << 16);
        *(u32x2*)&prow[2 * quad] = lo;      // k = 4*quad .. 4*quad+3
        *(u32x2*)&prow[8 + 2 * quad] = hi;  // k = 16+4*quad .. 16+4*quad+3
        __threadfence_block();  // wave-private LDS; DS ops in-order per wave
        // B-frag: lane (quad, l16=q) reads P[q][8*quad .. 8*quad+7]
        const short8v pf = *(const short8v*)&pl32[w][l16 * 20 + 4 * quad];
#pragma unroll
        for (int d = 0; d < 4; ++d)
            oaccT[d] = __builtin_amdgcn_mfma_f32_16x16x32_bf16(vf[d], pf, oaccT[d], 0, 0, 0);
        // rotate pipeline registers
#pragma unroll
        for (int sub = 0; sub < 2; ++sub)
#pragma unroll
            for (int hf = 0; hf < 2; ++hf) kf[sub][hf] = kf_n[sub][hf];
#pragma unroll
        for (int d = 0; d < 4; ++d) vf[d] = vf_n[d];
    }

    // epilogue: O[q][d] with q = q0+l16, d = df*16 + quad*4 + r -> 8B packed stores
    const float inv = 1.0f / lrow;
    const size_t rowbase = ((size_t)(b * S_LEN + q0 + l16)) * DM + h * HD;
#pragma unroll
    for (int df = 0; df < 4; ++df) {
        const int d0 = df * 16 + quad * 4;
        u32x2 ov;
        ov.x = (u32)f2bf(oaccT[df][0] * inv) | ((u32)f2bf(oaccT[df][1] * inv) << 16);
        ov.y = (u32)f2bf(oaccT[df][2] * inv) | ((u32)f2bf(oaccT[df][3] * inv) << 16);
        *(u32x2*)(ows + rowbase + d0) = ov;
    }
}

extern "C" void kernel_launch(void* const* d_in, const int* in_sizes, int n_in,
                              void* d_out, int out_size, void* d_ws, size_t ws_size,
                              hipStream_t stream) {
    const void* x = d_in[0];
    const void* w_qkv = d_in[1];
    const void* b_qkv = d_in[2];
    const void* w_out = d_in[3];
    const void* b_out = d_in[4];

    int* flag = (int*)d_ws;
    u16* qkv = (u16*)d_ws + 8;                      // 16B-aligned
    u16* qws = qkv + (size_t)TOK * 3 * DM;          // (B,H,S,64)
    u16* kws = qws + (size_t)NB * NH * S_LEN * HD;
    u16* vT = kws + (size_t)NB * NH * S_LEN * HD;   // (B,H,64,S)
    u16* ows = qkv;  // alias: qkv dead after rope_reorder + v_transpose

    detect_dtype<<<1, 256, 0, stream>>>((const u32*)x, flag);
    gemm_bt_bias<<<dim3(3 * DM / 128, TOK / 128), 256, 0, stream>>>(
        x, w_qkv, b_qkv, qkv, TOK, 3 * DM, DM, flag, 1, 1, 0);
    rope_reorder<<<(NB * S_LEN * NH * 32) / 256, 256, 0, stream>>>(qkv, qws, kws);
    v_transpose<<<dim3(S_LEN / 64, NH, NB), 256, 0, stream>>>(qkv, vT);
    attn_kernel<<<dim3(S_LEN / 64, NH, NB), 256, 0, stream>>>(qws, kws, vT, ows);
    gemm_bt_bias<<<dim3(DM / 128, TOK / 128), 256, 0, stream>>>(
        ows, w_out, b_out, d_out, TOK, DM, DM, flag, 0, 1, 1);
}

// Round 3
// 302.836 us; speedup vs baseline: 1.3843x; 1.3843x over previous
//
#include <hip/hip_runtime.h>
#include <stdint.h>

#define S_LEN 2048
#define NH 16
#define DM 1024
#define HD 64
#define NB 2
#define TOK (NB * S_LEN)  // 4096

typedef __attribute__((ext_vector_type(8))) short short8v;  // 8 bf16 = 4 VGPR
typedef __attribute__((ext_vector_type(4))) float f32x4;
typedef __attribute__((ext_vector_type(2))) unsigned int u32x2;
typedef unsigned short u16;
typedef unsigned int u32;

__device__ __forceinline__ float bf2f(u16 u) {
    u32 x = ((u32)u) << 16;
    return __builtin_bit_cast(float, x);
}
__device__ __forceinline__ u16 f2bf(float f) {  // RNE
    u32 u = __builtin_bit_cast(u32, f);
    return (u16)((u + 0x7FFFu + ((u >> 16) & 1u)) >> 16);
}

// async global->LDS, 16B per lane. LDS dest = wave-uniform base + lane*16 (HW).
// Generic LDS pointer = aperture(hi32) | offset(lo32): truncate to 32b offset.
__device__ __forceinline__ void gld_lds16(const void* g, void* lds_base_uniform) {
    auto gp = (const __attribute__((address_space(1))) u32*)(uintptr_t)g;
    auto lp = (__attribute__((address_space(3))) u32*)(uintptr_t)(u32)(uintptr_t)lds_base_uniform;
    __builtin_amdgcn_global_load_lds(gp, lp, 16, 0, 0);
}

// ---------------------------------------------------------------------------
// dtype sniffer: flag=1 if x is bf16, 0 if fp32. Samples low u16 of 4096 u32
// words (bf16 data -> sane exponents ~100%; fp32 data -> random mantissa ~25%).
// ---------------------------------------------------------------------------
__global__ void detect_dtype(const u32* __restrict__ xw, int* __restrict__ flag) {
    __shared__ int cnt[4];
    const int t = threadIdx.x;
    int c = 0;
#pragma unroll
    for (int j = 0; j < 16; ++j) {
        const u32 wd = xw[(t * 16 + j) * 64];  // spread over first 1MB
        const u32 e = (wd >> 7) & 0xFF;        // exponent of LOW u16 as bf16
        c += (e >= 0x58 && e <= 0x98) ? 1 : 0;
    }
#pragma unroll
    for (int off = 1; off < 64; off <<= 1) c += __shfl_xor(c, off);
    if ((t & 63) == 0) cnt[t >> 6] = c;
    __syncthreads();
    if (t == 0) flag[0] = (cnt[0] + cnt[1] + cnt[2] + cnt[3] >= 2600) ? 1 : 0;
}

// ---------------------------------------------------------------------------
// C[m,n] = sum_k A[m,k]*Bt[n,k] + bias[n]; fp32 accum. 128x128 tile, BK=32.
// Per-operand dtype: *_flagged ? (runtime flag: 1=bf16,0=fp32) : always bf16.
// ---------------------------------------------------------------------------
__global__ __launch_bounds__(256) void gemm_bt_bias(
    const void* __restrict__ Av, const void* __restrict__ Btv,
    const void* __restrict__ biasv, void* __restrict__ Cv,
    int M, int N, int K, const int* __restrict__ flagp,
    int a_flagged, int b_flagged, int out_flagged) {
    __shared__ __align__(16) u16 lA[128 * 32];
    __shared__ __align__(16) u16 lB[128 * 32];
    const int fl = flagp[0];
    const int fa = a_flagged ? fl : 1;
    const int fb = b_flagged ? fl : 1;
    const int fo = out_flagged ? fl : 1;

    const int tid = threadIdx.x;
    const int w = __builtin_amdgcn_readfirstlane(tid >> 6);
    const int lane = tid & 63;
    const int quad = lane >> 4;
    const int l16 = lane & 15;
    const int bm = blockIdx.y * 128;
    const int bn = blockIdx.x * 128;
    const int wm = (w >> 1) * 64;
    const int wn = (w & 1) * 64;

    f32x4 acc[4][4];
#pragma unroll
    for (int i = 0; i < 4; ++i)
#pragma unroll
        for (int j = 0; j < 4; ++j) acc[i][j] = {0.f, 0.f, 0.f, 0.f};

    const int kiters = K >> 5;
    for (int kk = 0; kk < kiters; ++kk) {
        __syncthreads();  // previous tile fully consumed
        if (fa) {
            const u16* A = (const u16*)Av;
#pragma unroll
            for (int c = 0; c < 2; ++c) {
                const int chunk = w * 2 + c;
                const int off = chunk * 1024 + lane * 16;  // byte off in 8KB tile
                const int m = off >> 6;
                const int kb = off & 63;
                gld_lds16((const char*)(A + (size_t)(bm + m) * K + kk * 32) + kb,
                          (char*)lA + chunk * 1024);
            }
        } else {
            const float* Af = (const float*)Av;
#pragma unroll
            for (int c = 0; c < 2; ++c) {
                const int e = (w * 2 + c) * 512 + lane * 8;  // element off in tile
                const int m = e >> 5, kc = e & 31;
                const float* ga = Af + (size_t)(bm + m) * K + kk * 32 + kc;
                const f32x4 v0 = *(const f32x4*)ga;
                const f32x4 v1 = *(const f32x4*)(ga + 4);
                short8v o;
#pragma unroll
                for (int q = 0; q < 4; ++q) o[q] = (short)f2bf(v0[q]);
#pragma unroll
                for (int q = 0; q < 4; ++q) o[4 + q] = (short)f2bf(v1[q]);
                *(short8v*)&lA[m * 32 + kc] = o;
            }
        }
        if (fb) {
            const u16* Bt = (const u16*)Btv;
#pragma unroll
            for (int c = 0; c < 2; ++c) {
                const int chunk = w * 2 + c;
                const int off = chunk * 1024 + lane * 16;
                const int m = off >> 6;
                const int kb = off & 63;
                gld_lds16((const char*)(Bt + (size_t)(bn + m) * K + kk * 32) + kb,
                          (char*)lB + chunk * 1024);
            }
        } else {
            const float* Btf = (const float*)Btv;
#pragma unroll
            for (int c = 0; c < 2; ++c) {
                const int e = (w * 2 + c) * 512 + lane * 8;
                const int m = e >> 5, kc = e & 31;
                const float* ga = Btf + (size_t)(bn + m) * K + kk * 32 + kc;
                const f32x4 v0 = *(const f32x4*)ga;
                const f32x4 v1 = *(const f32x4*)(ga + 4);
                short8v o;
#pragma unroll
                for (int q = 0; q < 4; ++q) o[q] = (short)f2bf(v0[q]);
#pragma unroll
                for (int q = 0; q < 4; ++q) o[4 + q] = (short)f2bf(v1[q]);
                *(short8v*)&lB[m * 32 + kc] = o;
            }
        }
        __syncthreads();  // drains vmcnt (async LDS loads) + lgkm + barrier

        short8v af[4], bf[4];
#pragma unroll
        for (int t = 0; t < 4; ++t) {
            af[t] = *(const short8v*)&lA[(wm + t * 16 + l16) * 32 + quad * 8];
            bf[t] = *(const short8v*)&lB[(wn + t * 16 + l16) * 32 + quad * 8];
        }
#pragma unroll
        for (int i = 0; i < 4; ++i)
#pragma unroll
            for (int j = 0; j < 4; ++j)
                acc[i][j] = __builtin_amdgcn_mfma_f32_16x16x32_bf16(af[i], bf[j], acc[i][j], 0, 0, 0);
    }

    // epilogue: C row = quad*4+r, col = lane&15 (m89/m91-verified layout)
#pragma unroll
    for (int j = 0; j < 4; ++j) {
        const int col = bn + wn + j * 16 + l16;
        const float bv = fl ? bf2f(((const u16*)biasv)[col]) : ((const float*)biasv)[col];
#pragma unroll
        for (int i = 0; i < 4; ++i) {
            const int row0 = bm + wm + i * 16 + quad * 4;
#pragma unroll
            for (int r = 0; r < 4; ++r) {
                const float val = acc[i][j][r] + bv;
                const size_t idx = (size_t)(row0 + r) * N + col;
                if (fo) ((u16*)Cv)[idx] = f2bf(val);
                else ((float*)Cv)[idx] = val;
            }
        }
    }
}

// ---------------------------------------------------------------------------
// RoPE on q,k + reorder to (B,H,S,64). One thread per rotation pair.
// ---------------------------------------------------------------------------
__global__ __launch_bounds__(256) void rope_reorder(
    const u16* __restrict__ qkv, u16* __restrict__ qws, u16* __restrict__ kws) {
    const int idx = blockIdx.x * 256 + threadIdx.x;  // B*S*H*32 = 2^21
    const int i = idx & 31;
    const int h = (idx >> 5) & 15;
    const int s = (idx >> 9) & 2047;
    const int b = idx >> 20;
    const u16* src = qkv + ((size_t)(b * S_LEN + s)) * (3 * DM) + h * HD + 2 * i;
    const u32 qp = *(const u32*)(src);
    const u32 kp = *(const u32*)(src + DM);
    const float q1 = bf2f((u16)qp), q2 = bf2f((u16)(qp >> 16));
    const float k1 = bf2f((u16)kp), k2 = bf2f((u16)(kp >> 16));
    const float freq = expf(-(float)(2 * i) * 0.14391156831212787f);  // 10000^(-2i/64)
    const float th = (float)s * freq;
    float sn, cs;
    sincosf(th, &sn, &cs);
    const float oq1 = q1 * cs - q2 * sn, oq2 = q1 * sn + q2 * cs;
    const float ok1 = k1 * cs - k2 * sn, ok2 = k1 * sn + k2 * cs;
    const size_t dst = ((size_t)((b * NH + h) * S_LEN + s)) * HD + 2 * i;
    *(u32*)(qws + dst) = (u32)f2bf(oq1) | ((u32)f2bf(oq2) << 16);
    *(u32*)(kws + dst) = (u32)f2bf(ok1) | ((u32)f2bf(ok2) << 16);
}

// ---------------------------------------------------------------------------
// V -> V^T (B,H,64,S) via padded LDS tile (PV A-operand must be K-contiguous)
// ---------------------------------------------------------------------------
__global__ __launch_bounds__(256) void v_transpose(
    const u16* __restrict__ qkv, u16* __restrict__ vT) {
    __shared__ u16 tile[64 * 65];
    const int s0 = blockIdx.x * 64;
    const int h = blockIdx.y, b = blockIdx.z;
    const int t = threadIdx.x;
#pragma unroll
    for (int it = 0; it < 16; ++it) {
        const int e = t + 256 * it;
        const int sl = e >> 6, d = e & 63;
        tile[sl * 65 + d] =
            qkv[((size_t)(b * S_LEN + s0 + sl)) * (3 * DM) + 2 * DM + h * HD + d];
    }
    __syncthreads();
#pragma unroll
    for (int it = 0; it < 16; ++it) {
        const int e = t + 256 * it;
        const int d = e >> 6, sl = e & 63;
        vT[((size_t)((b * NH + h) * HD + d)) * S_LEN + s0 + sl] = tile[sl * 65 + d];
    }
}

// ---------------------------------------------------------------------------
// Flash attention, swapped-operand, Sk=64 tiles, XCD-pinned, load-balanced.
//
// Grid: 1-D, 512 blocks. id = j*32 + g where g = (b,h) group (low 5 bits)
// and j = panel-pair index. Under round-robin dispatch->XCD, id%8 = g%8 so
// all 16 blocks of a head land on ONE XCD -> that head's K/V (512KB; 4 heads
// = 2MB) stays L2-resident -> load latency ~200cyc instead of ~900 (HBM).
//
// Load balance: wave handles strip in panel j AND panel 31-j (64-row panels)
// -> per-wave tile-work = (j+1)+(32-j) = 33, uniform across all waves.
//
// Sk=64: lane holds 16 scores of one q-row (swapped S^T = mfma(K,Q), q=l16);
// row max/sum = 15 in-lane tree ops + 2 shfl. Half the iterations/fences/
// rescales of Sk=32. Diagonal tiles are panel-aligned: mask condition
// (sub*16+quad*4+r > w*16+l16) is strip-independent. P staged per-wave in
// LDS (stride 36 u32 -> <=2-way banks, free), read back as b128 B-frags.
// O^T = mfma(V^T, P). Causal.
// ---------------------------------------------------------------------------
__global__ __launch_bounds__(256, 2) void attn_kernel(
    const u16* __restrict__ qws, const u16* __restrict__ kws,
    const u16* __restrict__ vT, u16* __restrict__ ows) {
    // per-wave private P staging: [wave][strip][16 q-rows][36 u32 (32 + pad)]
    __shared__ __align__(16) u32 pl32[4][2][16 * 36];  // 18 KB
    const int t = threadIdx.x;
    const int w = __builtin_amdgcn_readfirstlane(t >> 6);
    const int lane = t & 63;
    const int quad = lane >> 4;
    const int l16 = lane & 15;

    const int id = blockIdx.x;
    const int g = id & 31;   // (b,h) group - pinned to XCD g%8 (round-robin)
    const int j = id >> 5;   // 0..15 panel-pair index
    const int h = g & 15, b = g >> 4;

    const int panel[2] = {j, 31 - j};  // short, long
    int q0[2];
    q0[0] = panel[0] * 64 + w * 16;
    q0[1] = panel[1] * 64 + w * 16;
    const int ktl[2] = {panel[0], panel[1]};  // = (q0[st]+15)>>6
    const int qloc = w * 16 + l16;            // q offset within its panel

    const size_t bh = (size_t)(b * NH + h);
    const u16* qb = qws + bh * (size_t)S_LEN * HD;
    const u16* kb = kws + bh * (size_t)S_LEN * HD;
    const u16* vb = vT + bh * (size_t)HD * S_LEN;

    short8v qf[2][2];
#pragma unroll
    for (int st = 0; st < 2; ++st)
#pragma unroll
        for (int hf = 0; hf < 2; ++hf)
            qf[st][hf] = *(const short8v*)(qb + (size_t)(q0[st] + l16) * HD + hf * 32 + quad * 8);

    f32x4 oaccT[2][4];  // [strip][d-frag]: row = d (quad*4+r), col = q (l16)
    float mrow[2], lrow[2];
#pragma unroll
    for (int st = 0; st < 2; ++st) {
#pragma unroll
        for (int d = 0; d < 4; ++d) oaccT[st][d] = {0.f, 0.f, 0.f, 0.f};
        mrow[st] = -__builtin_inff();
        lrow[st] = 0.f;
    }

    for (int kt = 0; kt <= ktl[1]; ++kt) {
        // K tile fragments (shared by both strips): keys kt*64 .. kt*64+63
        short8v kf[4][2];
#pragma unroll
        for (int sub = 0; sub < 4; ++sub)
#pragma unroll
            for (int hf = 0; hf < 2; ++hf)
                kf[sub][hf] = *(const short8v*)(kb + (size_t)(kt * 64 + sub * 16 + l16) * HD +
                                               hf * 32 + quad * 8);
        // V^T tile fragments (issued early; consumed after softmax)
        short8v vf[2][4];
#pragma unroll
        for (int c = 0; c < 2; ++c)
#pragma unroll
            for (int d = 0; d < 4; ++d)
                vf[c][d] = *(const short8v*)(vb + (size_t)(d * 16 + l16) * S_LEN + kt * 64 +
                                             c * 32 + quad * 8);

#pragma unroll
        for (int st = 0; st < 2; ++st) {
            if (kt > ktl[st]) continue;  // strip 0 drops out after its range
            // S^T sub-tiles: row = k (quad*4+r within sub), col = q (l16)
            f32x4 s[4];
#pragma unroll
            for (int sub = 0; sub < 4; ++sub) {
                f32x4 a = {0.f, 0.f, 0.f, 0.f};
                a = __builtin_amdgcn_mfma_f32_16x16x32_bf16(kf[sub][0], qf[st][0], a, 0, 0, 0);
                a = __builtin_amdgcn_mfma_f32_16x16x32_bf16(kf[sub][1], qf[st][1], a, 0, 0, 0);
                s[sub] = a;
            }
            float sv[16];
#pragma unroll
            for (int sub = 0; sub < 4; ++sub)
#pragma unroll
                for (int r = 0; r < 4; ++r) sv[sub * 4 + r] = s[sub][r] * 0.125f;
            if (kt == ktl[st]) {  // diagonal tile (panel-aligned): mask k > q
#pragma unroll
                for (int sub = 0; sub < 4; ++sub)
#pragma unroll
                    for (int r = 0; r < 4; ++r)
                        if (sub * 16 + quad * 4 + r > qloc) sv[sub * 4 + r] = -__builtin_inff();
            }
            // per-q-row max: 15 in-lane (tree) + 2 cross-lane
            float a0 = fmaxf(sv[0], sv[1]), a1 = fmaxf(sv[2], sv[3]);
            float a2 = fmaxf(sv[4], sv[5]), a3 = fmaxf(sv[6], sv[7]);
            float a4 = fmaxf(sv[8], sv[9]), a5 = fmaxf(sv[10], sv[11]);
            float a6 = fmaxf(sv[12], sv[13]), a7 = fmaxf(sv[14], sv[15]);
            a0 = fmaxf(a0, a1); a2 = fmaxf(a2, a3);
            a4 = fmaxf(a4, a5); a6 = fmaxf(a6, a7);
            a0 = fmaxf(a0, a2); a4 = fmaxf(a4, a6);
            float mx = fmaxf(a0, a4);
            mx = fmaxf(mx, __shfl_xor(mx, 16));
            mx = fmaxf(mx, __shfl_xor(mx, 32));
            const float mnew = fmaxf(mrow[st], mx);
            const float alpha = __expf(mrow[st] - mnew);
            mrow[st] = mnew;
            float p[16];
#pragma unroll
            for (int i = 0; i < 16; ++i) p[i] = __expf(sv[i] - mnew);
            float b0 = p[0] + p[1], b1 = p[2] + p[3], b2 = p[4] + p[5], b3 = p[6] + p[7];
            float b4 = p[8] + p[9], b5 = p[10] + p[11], b6 = p[12] + p[13], b7 = p[14] + p[15];
            b0 += b1; b2 += b3; b4 += b5; b6 += b7;
            b0 += b2; b4 += b6;
            float ps = b0 + b4;
            ps += __shfl_xor(ps, 16);
            ps += __shfl_xor(ps, 32);
            lrow[st] = lrow[st] * alpha + ps;
#pragma unroll
            for (int d = 0; d < 4; ++d) oaccT[st][d] *= alpha;
            // pack P[q=l16][k] to bf16 pairs; 4x b64 writes
            u32* prow = &pl32[w][st][l16 * 36];
#pragma unroll
            for (int sub = 0; sub < 4; ++sub) {
                u32x2 pw;
                pw.x = (u32)f2bf(p[sub * 4 + 0]) | ((u32)f2bf(p[sub * 4 + 1]) << 16);
                pw.y = (u32)f2bf(p[sub * 4 + 2]) | ((u32)f2bf(p[sub * 4 + 3]) << 16);
                *(u32x2*)&prow[sub * 8 + quad * 2] = pw;  // keys sub*16+quad*4..+3
            }
        }
        __threadfence_block();  // wave-private LDS; DS ops in-order per wave
#pragma unroll
        for (int st = 0; st < 2; ++st) {
            if (kt > ktl[st]) continue;
            const u32* prow = &pl32[w][st][l16 * 36];
#pragma unroll
            for (int c = 0; c < 2; ++c) {
                // B-frag: lane (quad, l16=q) reads P[q][c*32 + quad*8 .. +7]
                const short8v pf = *(const short8v*)&prow[c * 16 + quad * 4];
#pragma unroll
                for (int d = 0; d < 4; ++d)
                    oaccT[st][d] =
                        __builtin_amdgcn_mfma_f32_16x16x32_bf16(vf[c][d], pf, oaccT[st][d], 0, 0, 0);
            }
        }
    }

    // epilogue: O[q][d] with q = q0+l16, d = df*16 + quad*4 + r -> 8B packed stores
#pragma unroll
    for (int st = 0; st < 2; ++st) {
        const float inv = 1.0f / lrow[st];
        const size_t rowbase = ((size_t)(b * S_LEN + q0[st] + l16)) * DM + h * HD;
#pragma unroll
        for (int df = 0; df < 4; ++df) {
            const int d0 = df * 16 + quad * 4;
            u32x2 ov;
            ov.x = (u32)f2bf(oaccT[st][df][0] * inv) | ((u32)f2bf(oaccT[st][df][1] * inv) << 16);
            ov.y = (u32)f2bf(oaccT[st][df][2] * inv) | ((u32)f2bf(oaccT[st][df][3] * inv) << 16);
            *(u32x2*)(ows + rowbase + d0) = ov;
        }
    }
}

extern "C" void kernel_launch(void* const* d_in, const int* in_sizes, int n_in,
                              void* d_out, int out_size, void* d_ws, size_t ws_size,
                              hipStream_t stream) {
    const void* x = d_in[0];
    const void* w_qkv = d_in[1];
    const void* b_qkv = d_in[2];
    const void* w_out = d_in[3];
    const void* b_out = d_in[4];

    int* flag = (int*)d_ws;
    u16* qkv = (u16*)d_ws + 8;                      // 16B-aligned
    u16* qws = qkv + (size_t)TOK * 3 * DM;          // (B,H,S,64)
    u16* kws = qws + (size_t)NB * NH * S_LEN * HD;
    u16* vT = kws + (size_t)NB * NH * S_LEN * HD;   // (B,H,64,S)
    u16* ows = qkv;  // alias: qkv dead after rope_reorder + v_transpose

    detect_dtype<<<1, 256, 0, stream>>>((const u32*)x, flag);
    gemm_bt_bias<<<dim3(3 * DM / 128, TOK / 128), 256, 0, stream>>>(
        x, w_qkv, b_qkv, qkv, TOK, 3 * DM, DM, flag, 1, 1, 0);
    rope_reorder<<<(NB * S_LEN * NH * 32) / 256, 256, 0, stream>>>(qkv, qws, kws);
    v_transpose<<<dim3(S_LEN / 64, NH, NB), 256, 0, stream>>>(qkv, vT);
    // 1-D grid: id = j*32 + g, g=(b,h). 512 blocks total.
    attn_kernel<<<dim3((S_LEN / 128) * NH * NB), 256, 0, stream>>>(qws, kws, vT, ows);
    gemm_bt_bias<<<dim3(DM / 128, TOK / 128), 256, 0, stream>>>(
        ows, w_out, b_out, d_out, TOK, DM, DM, flag, 0, 1, 1);
}

// Round 4
// 274.636 us; speedup vs baseline: 1.5264x; 1.1027x over previous
//
#include <hip/hip_runtime.h>
#include <stdint.h>

#define S_LEN 2048
#define NH 16
#define DM 1024
#define HD 64
#define NB 2
#define TOK (NB * S_LEN)  // 4096

typedef __attribute__((ext_vector_type(8))) short short8v;  // 8 bf16 = 4 VGPR
typedef __attribute__((ext_vector_type(4))) float f32x4;
typedef __attribute__((ext_vector_type(2))) unsigned int u32x2;
typedef unsigned short u16;
typedef unsigned int u32;

__device__ __forceinline__ float bf2f(u16 u) {
    u32 x = ((u32)u) << 16;
    return __builtin_bit_cast(float, x);
}
__device__ __forceinline__ u16 f2bf(float f) {  // RNE
    u32 u = __builtin_bit_cast(u32, f);
    return (u16)((u + 0x7FFFu + ((u >> 16) & 1u)) >> 16);
}

// async global->LDS, 16B per lane. LDS dest = wave-uniform base + lane*16 (HW).
// Generic LDS pointer = aperture(hi32) | offset(lo32): truncate to 32b offset.
__device__ __forceinline__ void gld_lds16(const void* g, void* lds_base_uniform) {
    auto gp = (const __attribute__((address_space(1))) u32*)(uintptr_t)g;
    auto lp = (__attribute__((address_space(3))) u32*)(uintptr_t)(u32)(uintptr_t)lds_base_uniform;
    __builtin_amdgcn_global_load_lds(gp, lp, 16, 0, 0);
}

// ---------------------------------------------------------------------------
// dtype sniffer: flag=1 if x is bf16, 0 if fp32. Samples low u16 of 4096 u32
// words (bf16 data -> sane exponents ~100%; fp32 data -> random mantissa ~25%).
// ---------------------------------------------------------------------------
__global__ void detect_dtype(const u32* __restrict__ xw, int* __restrict__ flag) {
    __shared__ int cnt[4];
    const int t = threadIdx.x;
    int c = 0;
#pragma unroll
    for (int j = 0; j < 16; ++j) {
        const u32 wd = xw[(t * 16 + j) * 64];  // spread over first 1MB
        const u32 e = (wd >> 7) & 0xFF;        // exponent of LOW u16 as bf16
        c += (e >= 0x58 && e <= 0x98) ? 1 : 0;
    }
#pragma unroll
    for (int off = 1; off < 64; off <<= 1) c += __shfl_xor(c, off);
    if ((t & 63) == 0) cnt[t >> 6] = c;
    __syncthreads();
    if (t == 0) flag[0] = (cnt[0] + cnt[1] + cnt[2] + cnt[3] >= 2600) ? 1 : 0;
}

// ---------------------------------------------------------------------------
// fp32 -> bf16 conversion (or straight copy when input already bf16).
// 8 elements per thread; grid = n/2048 blocks of 256.
// ---------------------------------------------------------------------------
__global__ __launch_bounds__(256) void convert_bf16(
    const void* __restrict__ src, u16* __restrict__ dst, const int* __restrict__ flagp) {
    const int i = blockIdx.x * 256 + threadIdx.x;  // index of 8-elem chunk
    if (flagp[0]) {
        ((short8v*)dst)[i] = ((const short8v*)src)[i];
    } else {
        const f32x4 v0 = ((const f32x4*)src)[2 * i];
        const f32x4 v1 = ((const f32x4*)src)[2 * i + 1];
        short8v o;
#pragma unroll
        for (int q = 0; q < 4; ++q) o[q] = (short)f2bf(v0[q]);
#pragma unroll
        for (int q = 0; q < 4; ++q) o[4 + q] = (short)f2bf(v1[q]);
        ((short8v*)dst)[i] = o;
    }
}

// ---------------------------------------------------------------------------
// C[m,n] = sum_k A[m,k]*Bt[n,k] + bias[n]; fp32 accum. 128x128 tile, BK=32.
// Per-operand dtype: *_flagged ? (runtime flag: 1=bf16,0=fp32) : always bf16.
// (After upfront conversion both GEMMs run the pure-bf16 gld_lds path.)
// ---------------------------------------------------------------------------
__global__ __launch_bounds__(256) void gemm_bt_bias(
    const void* __restrict__ Av, const void* __restrict__ Btv,
    const void* __restrict__ biasv, void* __restrict__ Cv,
    int M, int N, int K, const int* __restrict__ flagp,
    int a_flagged, int b_flagged, int out_flagged) {
    __shared__ __align__(16) u16 lA[128 * 32];
    __shared__ __align__(16) u16 lB[128 * 32];
    const int fl = flagp[0];
    const int fa = a_flagged ? fl : 1;
    const int fb = b_flagged ? fl : 1;
    const int fo = out_flagged ? fl : 1;

    const int tid = threadIdx.x;
    const int w = __builtin_amdgcn_readfirstlane(tid >> 6);
    const int lane = tid & 63;
    const int quad = lane >> 4;
    const int l16 = lane & 15;
    const int bm = blockIdx.y * 128;
    const int bn = blockIdx.x * 128;
    const int wm = (w >> 1) * 64;
    const int wn = (w & 1) * 64;

    f32x4 acc[4][4];
#pragma unroll
    for (int i = 0; i < 4; ++i)
#pragma unroll
        for (int j = 0; j < 4; ++j) acc[i][j] = {0.f, 0.f, 0.f, 0.f};

    const int kiters = K >> 5;
    for (int kk = 0; kk < kiters; ++kk) {
        __syncthreads();  // previous tile fully consumed
        if (fa) {
            const u16* A = (const u16*)Av;
#pragma unroll
            for (int c = 0; c < 2; ++c) {
                const int chunk = w * 2 + c;
                const int off = chunk * 1024 + lane * 16;  // byte off in 8KB tile
                const int m = off >> 6;
                const int kb = off & 63;
                gld_lds16((const char*)(A + (size_t)(bm + m) * K + kk * 32) + kb,
                          (char*)lA + chunk * 1024);
            }
        } else {
            const float* Af = (const float*)Av;
#pragma unroll
            for (int c = 0; c < 2; ++c) {
                const int e = (w * 2 + c) * 512 + lane * 8;  // element off in tile
                const int m = e >> 5, kc = e & 31;
                const float* ga = Af + (size_t)(bm + m) * K + kk * 32 + kc;
                const f32x4 v0 = *(const f32x4*)ga;
                const f32x4 v1 = *(const f32x4*)(ga + 4);
                short8v o;
#pragma unroll
                for (int q = 0; q < 4; ++q) o[q] = (short)f2bf(v0[q]);
#pragma unroll
                for (int q = 0; q < 4; ++q) o[4 + q] = (short)f2bf(v1[q]);
                *(short8v*)&lA[m * 32 + kc] = o;
            }
        }
        if (fb) {
            const u16* Bt = (const u16*)Btv;
#pragma unroll
            for (int c = 0; c < 2; ++c) {
                const int chunk = w * 2 + c;
                const int off = chunk * 1024 + lane * 16;
                const int m = off >> 6;
                const int kb = off & 63;
                gld_lds16((const char*)(Bt + (size_t)(bn + m) * K + kk * 32) + kb,
                          (char*)lB + chunk * 1024);
            }
        } else {
            const float* Btf = (const float*)Btv;
#pragma unroll
            for (int c = 0; c < 2; ++c) {
                const int e = (w * 2 + c) * 512 + lane * 8;
                const int m = e >> 5, kc = e & 31;
                const float* ga = Btf + (size_t)(bn + m) * K + kk * 32 + kc;
                const f32x4 v0 = *(const f32x4*)ga;
                const f32x4 v1 = *(const f32x4*)(ga + 4);
                short8v o;
#pragma unroll
                for (int q = 0; q < 4; ++q) o[q] = (short)f2bf(v0[q]);
#pragma unroll
                for (int q = 0; q < 4; ++q) o[4 + q] = (short)f2bf(v1[q]);
                *(short8v*)&lB[m * 32 + kc] = o;
            }
        }
        __syncthreads();  // drains vmcnt (async LDS loads) + lgkm + barrier

        short8v af[4], bf[4];
#pragma unroll
        for (int t = 0; t < 4; ++t) {
            af[t] = *(const short8v*)&lA[(wm + t * 16 + l16) * 32 + quad * 8];
            bf[t] = *(const short8v*)&lB[(wn + t * 16 + l16) * 32 + quad * 8];
        }
#pragma unroll
        for (int i = 0; i < 4; ++i)
#pragma unroll
            for (int j = 0; j < 4; ++j)
                acc[i][j] = __builtin_amdgcn_mfma_f32_16x16x32_bf16(af[i], bf[j], acc[i][j], 0, 0, 0);
    }

    // epilogue: C row = quad*4+r, col = lane&15 (m89/m91-verified layout)
#pragma unroll
    for (int j = 0; j < 4; ++j) {
        const int col = bn + wn + j * 16 + l16;
        const float bv = fl ? bf2f(((const u16*)biasv)[col]) : ((const float*)biasv)[col];
#pragma unroll
        for (int i = 0; i < 4; ++i) {
            const int row0 = bm + wm + i * 16 + quad * 4;
#pragma unroll
            for (int r = 0; r < 4; ++r) {
                const float val = acc[i][j][r] + bv;
                const size_t idx = (size_t)(row0 + r) * N + col;
                if (fo) ((u16*)Cv)[idx] = f2bf(val);
                else ((float*)Cv)[idx] = val;
            }
        }
    }
}

// ---------------------------------------------------------------------------
// RoPE on q,k + reorder to (B,H,S,64). One thread per rotation pair.
// ---------------------------------------------------------------------------
__global__ __launch_bounds__(256) void rope_reorder(
    const u16* __restrict__ qkv, u16* __restrict__ qws, u16* __restrict__ kws) {
    const int idx = blockIdx.x * 256 + threadIdx.x;  // B*S*H*32 = 2^21
    const int i = idx & 31;
    const int h = (idx >> 5) & 15;
    const int s = (idx >> 9) & 2047;
    const int b = idx >> 20;
    const u16* src = qkv + ((size_t)(b * S_LEN + s)) * (3 * DM) + h * HD + 2 * i;
    const u32 qp = *(const u32*)(src);
    const u32 kp = *(const u32*)(src + DM);
    const float q1 = bf2f((u16)qp), q2 = bf2f((u16)(qp >> 16));
    const float k1 = bf2f((u16)kp), k2 = bf2f((u16)(kp >> 16));
    const float freq = expf(-(float)(2 * i) * 0.14391156831212787f);  // 10000^(-2i/64)
    const float th = (float)s * freq;
    float sn, cs;
    sincosf(th, &sn, &cs);
    const float oq1 = q1 * cs - q2 * sn, oq2 = q1 * sn + q2 * cs;
    const float ok1 = k1 * cs - k2 * sn, ok2 = k1 * sn + k2 * cs;
    const size_t dst = ((size_t)((b * NH + h) * S_LEN + s)) * HD + 2 * i;
    *(u32*)(qws + dst) = (u32)f2bf(oq1) | ((u32)f2bf(oq2) << 16);
    *(u32*)(kws + dst) = (u32)f2bf(ok1) | ((u32)f2bf(ok2) << 16);
}

// ---------------------------------------------------------------------------
// V -> V^T (B,H,64,S) via padded LDS tile (PV A-operand must be K-contiguous)
// ---------------------------------------------------------------------------
__global__ __launch_bounds__(256) void v_transpose(
    const u16* __restrict__ qkv, u16* __restrict__ vT) {
    __shared__ u16 tile[64 * 65];
    const int s0 = blockIdx.x * 64;
    const int h = blockIdx.y, b = blockIdx.z;
    const int t = threadIdx.x;
#pragma unroll
    for (int it = 0; it < 16; ++it) {
        const int e = t + 256 * it;
        const int sl = e >> 6, d = e & 63;
        tile[sl * 65 + d] =
            qkv[((size_t)(b * S_LEN + s0 + sl)) * (3 * DM) + 2 * DM + h * HD + d];
    }
    __syncthreads();
#pragma unroll
    for (int it = 0; it < 16; ++it) {
        const int e = t + 256 * it;
        const int d = e >> 6, sl = e & 63;
        vT[((size_t)((b * NH + h) * HD + d)) * S_LEN + s0 + sl] = tile[sl * 65 + d];
    }
}

// ---------------------------------------------------------------------------
// Flash attention, swapped-operand, Sk=64, XCD-pinned, contiguous-32-row
// waves, longest-first dispatch.
//
// Grid: 1-D, 1024 blocks of 128 threads (2 waves). id = qbr*32 + g where
// g = (b,h) (low 5 bits -> XCD pin: all blocks of a head land on XCD g%8,
// K/V stay L2-resident; R3-verified: FETCH 74.6 -> 12.3 MB). qb = 31-qbr
// so longest blocks dispatch first (backfill-friendly).
//
// Each wave owns 32 CONTIGUOUS q-rows (q0 = qb*64 + w*32) as two 16-col
// B-frag halves sharing one kt loop: both waves of a block have IDENTICAL
// trip count (qb+1), every iteration feeds 32 active rows -> total wave-
// iterations drop 1568 -> 1056 per (b,h) vs R3 pairing, and 1024 blocks @
// ~4 resident/CU backfill the 1..32-iteration spread.
//
// S^T = mfma(K,Q): lane holds 16 scores of one q-row; row max/sum = 15
// in-lane tree ops + 2 shfl. P packed bf16 in-register, staged via 4x
// ds_write_b64 into stride-36-u32 rows (<=2-way banks), read as b128
// B-frags. O^T = mfma(V^T, P). Causal: single masked tile (kt == qb).
// ---------------------------------------------------------------------------
__global__ __launch_bounds__(128, 2) void attn_kernel(
    const u16* __restrict__ qws, const u16* __restrict__ kws,
    const u16* __restrict__ vT, u16* __restrict__ ows) {
    // per-wave-half P staging: [wave][half][16 q-rows][36 u32 (32 + pad)]
    __shared__ __align__(16) u32 pl32[2][2][16 * 36];  // 9216 B
    const int t = threadIdx.x;
    const int w = __builtin_amdgcn_readfirstlane(t >> 6);
    const int lane = t & 63;
    const int quad = lane >> 4;
    const int l16 = lane & 15;

    const int id = blockIdx.x;
    const int g = id & 31;        // (b,h) group - pinned to XCD g%8
    const int qb = 31 - (id >> 5);  // longest-first
    const int h = g & 15, b = g >> 4;
    const int q0 = qb * 64 + w * 32;  // wave's first q-row

    const size_t bh = (size_t)(b * NH + h);
    const u16* qb_ = qws + bh * (size_t)S_LEN * HD;
    const u16* kb = kws + bh * (size_t)S_LEN * HD;
    const u16* vb = vT + bh * (size_t)HD * S_LEN;

    short8v qf[2][2];  // [half][hf]
#pragma unroll
    for (int hh = 0; hh < 2; ++hh)
#pragma unroll
        for (int hf = 0; hf < 2; ++hf)
            qf[hh][hf] =
                *(const short8v*)(qb_ + (size_t)(q0 + hh * 16 + l16) * HD + hf * 32 + quad * 8);

    f32x4 oaccT[2][4];  // [half][d-frag]: row = d (quad*4+r), col = q (l16)
    float mrow[2], lrow[2];
#pragma unroll
    for (int hh = 0; hh < 2; ++hh) {
#pragma unroll
        for (int d = 0; d < 4; ++d) oaccT[hh][d] = {0.f, 0.f, 0.f, 0.f};
        mrow[hh] = -__builtin_inff();
        lrow[hh] = 0.f;
    }

    for (int kt = 0; kt <= qb; ++kt) {
        // K tile fragments (shared by both halves): keys kt*64 .. kt*64+63
        short8v kf[4][2];
#pragma unroll
        for (int sub = 0; sub < 4; ++sub)
#pragma unroll
            for (int hf = 0; hf < 2; ++hf)
                kf[sub][hf] = *(const short8v*)(kb + (size_t)(kt * 64 + sub * 16 + l16) * HD +
                                               hf * 32 + quad * 8);
        // V^T tile fragments (issued early; consumed after softmax)
        short8v vf[2][4];
#pragma unroll
        for (int c = 0; c < 2; ++c)
#pragma unroll
            for (int d = 0; d < 4; ++d)
                vf[c][d] = *(const short8v*)(vb + (size_t)(d * 16 + l16) * S_LEN + kt * 64 +
                                             c * 32 + quad * 8);

#pragma unroll
        for (int hh = 0; hh < 2; ++hh) {
            // S^T sub-tiles: row = k (quad*4+r within sub), col = q (l16)
            f32x4 s[4];
#pragma unroll
            for (int sub = 0; sub < 4; ++sub) {
                f32x4 a = {0.f, 0.f, 0.f, 0.f};
                a = __builtin_amdgcn_mfma_f32_16x16x32_bf16(kf[sub][0], qf[hh][0], a, 0, 0, 0);
                a = __builtin_amdgcn_mfma_f32_16x16x32_bf16(kf[sub][1], qf[hh][1], a, 0, 0, 0);
                s[sub] = a;
            }
            float sv[16];
#pragma unroll
            for (int sub = 0; sub < 4; ++sub)
#pragma unroll
                for (int r = 0; r < 4; ++r) sv[sub * 4 + r] = s[sub][r] * 0.125f;
            if (kt == qb) {  // single masked tile: k > q -> -inf
                const int qg = q0 + hh * 16 + l16;
#pragma unroll
                for (int sub = 0; sub < 4; ++sub)
#pragma unroll
                    for (int r = 0; r < 4; ++r)
                        if (kt * 64 + sub * 16 + quad * 4 + r > qg)
                            sv[sub * 4 + r] = -__builtin_inff();
            }
            // per-q-row max: 15 in-lane (tree) + 2 cross-lane
            float a0 = fmaxf(sv[0], sv[1]), a1 = fmaxf(sv[2], sv[3]);
            float a2 = fmaxf(sv[4], sv[5]), a3 = fmaxf(sv[6], sv[7]);
            float a4 = fmaxf(sv[8], sv[9]), a5 = fmaxf(sv[10], sv[11]);
            float a6 = fmaxf(sv[12], sv[13]), a7 = fmaxf(sv[14], sv[15]);
            a0 = fmaxf(a0, a1); a2 = fmaxf(a2, a3);
            a4 = fmaxf(a4, a5); a6 = fmaxf(a6, a7);
            a0 = fmaxf(a0, a2); a4 = fmaxf(a4, a6);
            float mx = fmaxf(a0, a4);
            mx = fmaxf(mx, __shfl_xor(mx, 16));
            mx = fmaxf(mx, __shfl_xor(mx, 32));
            const float mnew = fmaxf(mrow[hh], mx);
            const float alpha = __expf(mrow[hh] - mnew);
            mrow[hh] = mnew;
            float p[16];
#pragma unroll
            for (int i = 0; i < 16; ++i) p[i] = __expf(sv[i] - mnew);
            float b0 = p[0] + p[1], b1 = p[2] + p[3], b2 = p[4] + p[5], b3 = p[6] + p[7];
            float b4 = p[8] + p[9], b5 = p[10] + p[11], b6 = p[12] + p[13], b7 = p[14] + p[15];
            b0 += b1; b2 += b3; b4 += b5; b6 += b7;
            b0 += b2; b4 += b6;
            float ps = b0 + b4;
            ps += __shfl_xor(ps, 16);
            ps += __shfl_xor(ps, 32);
            lrow[hh] = lrow[hh] * alpha + ps;
#pragma unroll
            for (int d = 0; d < 4; ++d) oaccT[hh][d] *= alpha;
            // pack P[q=l16][k] to bf16 pairs; 4x b64 writes
            u32* prow = &pl32[w][hh][l16 * 36];
#pragma unroll
            for (int sub = 0; sub < 4; ++sub) {
                u32x2 pw;
                pw.x = (u32)f2bf(p[sub * 4 + 0]) | ((u32)f2bf(p[sub * 4 + 1]) << 16);
                pw.y = (u32)f2bf(p[sub * 4 + 2]) | ((u32)f2bf(p[sub * 4 + 3]) << 16);
                *(u32x2*)&prow[sub * 8 + quad * 2] = pw;  // keys sub*16+quad*4..+3
            }
        }
        __threadfence_block();  // wave-private LDS; DS ops in-order per wave
#pragma unroll
        for (int hh = 0; hh < 2; ++hh) {
            const u32* prow = &pl32[w][hh][l16 * 36];
#pragma unroll
            for (int c = 0; c < 2; ++c) {
                // B-frag: lane (quad, l16=q) reads P[q][c*32 + quad*8 .. +7]
                const short8v pf = *(const short8v*)&prow[c * 16 + quad * 4];
#pragma unroll
                for (int d = 0; d < 4; ++d)
                    oaccT[hh][d] =
                        __builtin_amdgcn_mfma_f32_16x16x32_bf16(vf[c][d], pf, oaccT[hh][d], 0, 0, 0);
            }
        }
    }

    // epilogue: O[q][d] with q = q0+hh*16+l16, d = df*16+quad*4+r -> 8B stores
#pragma unroll
    for (int hh = 0; hh < 2; ++hh) {
        const float inv = 1.0f / lrow[hh];
        const size_t rowbase = ((size_t)(b * S_LEN + q0 + hh * 16 + l16)) * DM + h * HD;
#pragma unroll
        for (int df = 0; df < 4; ++df) {
            const int d0 = df * 16 + quad * 4;
            u32x2 ov;
            ov.x = (u32)f2bf(oaccT[hh][df][0] * inv) | ((u32)f2bf(oaccT[hh][df][1] * inv) << 16);
            ov.y = (u32)f2bf(oaccT[hh][df][2] * inv) | ((u32)f2bf(oaccT[hh][df][3] * inv) << 16);
            *(u32x2*)(ows + rowbase + d0) = ov;
        }
    }
}

extern "C" void kernel_launch(void* const* d_in, const int* in_sizes, int n_in,
                              void* d_out, int out_size, void* d_ws, size_t ws_size,
                              hipStream_t stream) {
    const void* x = d_in[0];
    const void* w_qkv = d_in[1];
    const void* b_qkv = d_in[2];
    const void* w_out = d_in[3];
    const void* b_out = d_in[4];

    int* flag = (int*)d_ws;
    u16* qkv = (u16*)d_ws + 8;                      // 16B-aligned, 24 MB
    u16* qws = qkv + (size_t)TOK * 3 * DM;          // (B,H,S,64), 8 MB
    u16* kws = qws + (size_t)NB * NH * S_LEN * HD;  // 8 MB
    u16* vT = kws + (size_t)NB * NH * S_LEN * HD;   // (B,H,64,S), 8 MB
    u16* woutb = vT + (size_t)NB * NH * HD * S_LEN; // 2 MB
    u16* ows = qkv;    // alias: qkv dead after rope_reorder + v_transpose
    u16* xb = qws;     // alias: xb dead before rope_reorder writes qws
    u16* wqkvb = kws;  // alias: wqkvb dead before rope_reorder writes kws

    detect_dtype<<<1, 256, 0, stream>>>((const u32*)x, flag);
    // upfront bf16 conversion (copy-through when already bf16)
    convert_bf16<<<(TOK * DM) / 2048, 256, 0, stream>>>(x, xb, flag);
    convert_bf16<<<(3 * DM * DM) / 2048, 256, 0, stream>>>(w_qkv, wqkvb, flag);
    convert_bf16<<<(DM * DM) / 2048, 256, 0, stream>>>(w_out, woutb, flag);

    gemm_bt_bias<<<dim3(3 * DM / 128, TOK / 128), 256, 0, stream>>>(
        xb, wqkvb, b_qkv, qkv, TOK, 3 * DM, DM, flag, 0, 0, 0);
    rope_reorder<<<(NB * S_LEN * NH * 32) / 256, 256, 0, stream>>>(qkv, qws, kws);
    v_transpose<<<dim3(S_LEN / 64, NH, NB), 256, 0, stream>>>(qkv, vT);
    // 1-D grid: id = qbr*32 + g, g=(b,h). 1024 blocks x 128 threads.
    attn_kernel<<<dim3(32 * 32), 128, 0, stream>>>(qws, kws, vT, ows);
    gemm_bt_bias<<<dim3(DM / 128, TOK / 128), 256, 0, stream>>>(
        ows, woutb, b_out, d_out, TOK, DM, DM, flag, 0, 0, 1);
}

// Round 5
// 253.499 us; speedup vs baseline: 1.6537x; 1.0834x over previous
//
#include <hip/hip_runtime.h>
#include <stdint.h>

#define S_LEN 2048
#define NH 16
#define DM 1024
#define HD 64
#define NB 2
#define TOK (NB * S_LEN)  // 4096

typedef __attribute__((ext_vector_type(8))) short short8v;  // 8 bf16 = 4 VGPR
typedef __attribute__((ext_vector_type(4))) float f32x4;
typedef __attribute__((ext_vector_type(2))) unsigned int u32x2;
typedef unsigned short u16;
typedef unsigned int u32;

__device__ __forceinline__ float bf2f(u16 u) {
    u32 x = ((u32)u) << 16;
    return __builtin_bit_cast(float, x);
}
__device__ __forceinline__ u16 f2bf(float f) {  // RNE
    u32 u = __builtin_bit_cast(u32, f);
    return (u16)((u + 0x7FFFu + ((u >> 16) & 1u)) >> 16);
}

// async global->LDS, 16B per lane. LDS dest = wave-uniform base + lane*16 (HW).
// Generic LDS pointer = aperture(hi32) | offset(lo32): truncate to 32b offset.
__device__ __forceinline__ void gld_lds16(const void* g, void* lds_base_uniform) {
    auto gp = (const __attribute__((address_space(1))) u32*)(uintptr_t)g;
    auto lp = (__attribute__((address_space(3))) u32*)(uintptr_t)(u32)(uintptr_t)lds_base_uniform;
    __builtin_amdgcn_global_load_lds(gp, lp, 16, 0, 0);
}

// ---------------------------------------------------------------------------
// dtype sniffer: flag=1 if x is bf16, 0 if fp32. Samples low u16 of 4096 u32
// words (bf16 data -> sane exponents ~100%; fp32 data -> random mantissa ~25%).
// ---------------------------------------------------------------------------
__global__ void detect_dtype(const u32* __restrict__ xw, int* __restrict__ flag) {
    __shared__ int cnt[4];
    const int t = threadIdx.x;
    int c = 0;
#pragma unroll
    for (int j = 0; j < 16; ++j) {
        const u32 wd = xw[(t * 16 + j) * 64];  // spread over first 1MB
        const u32 e = (wd >> 7) & 0xFF;        // exponent of LOW u16 as bf16
        c += (e >= 0x58 && e <= 0x98) ? 1 : 0;
    }
#pragma unroll
    for (int off = 1; off < 64; off <<= 1) c += __shfl_xor(c, off);
    if ((t & 63) == 0) cnt[t >> 6] = c;
    __syncthreads();
    if (t == 0) flag[0] = (cnt[0] + cnt[1] + cnt[2] + cnt[3] >= 2600) ? 1 : 0;
}

// ---------------------------------------------------------------------------
// Fused fp32 -> bf16 conversion of x, w_qkv, w_out (copy-through when bf16).
// One grid: chunk index ranges partition the three buffers. 8 elems/thread.
// ---------------------------------------------------------------------------
#define XCH (TOK * DM / 8)           // 524288
#define WQCH (3 * DM * DM / 8)       // 393216
#define WOCH (DM * DM / 8)           // 131072
__global__ __launch_bounds__(256) void convert_all(
    const void* __restrict__ xs, const void* __restrict__ wqs, const void* __restrict__ wos,
    u16* __restrict__ xd, u16* __restrict__ wqd, u16* __restrict__ wod,
    const int* __restrict__ flagp) {
    int i = blockIdx.x * 256 + threadIdx.x;
    const void* src;
    u16* dst;
    if (i < XCH) {
        src = xs; dst = xd;
    } else if (i < XCH + WQCH) {
        src = wqs; dst = wqd; i -= XCH;
    } else {
        src = wos; dst = wod; i -= XCH + WQCH;
    }
    if (flagp[0]) {
        ((short8v*)dst)[i] = ((const short8v*)src)[i];
    } else {
        const f32x4 v0 = ((const f32x4*)src)[2 * i];
        const f32x4 v1 = ((const f32x4*)src)[2 * i + 1];
        short8v o;
#pragma unroll
        for (int q = 0; q < 4; ++q) o[q] = (short)f2bf(v0[q]);
#pragma unroll
        for (int q = 0; q < 4; ++q) o[4 + q] = (short)f2bf(v1[q]);
        ((short8v*)dst)[i] = o;
    }
}

// ---------------------------------------------------------------------------
// C[m,n] = sum_k A[m,k]*Bt[n,k] + bias[n]; fp32 accum. 128x128 tile, BK=32.
// Per-operand dtype: *_flagged ? (runtime flag: 1=bf16,0=fp32) : always bf16.
// (After upfront conversion both GEMMs run the pure-bf16 gld_lds path.)
// ---------------------------------------------------------------------------
__global__ __launch_bounds__(256) void gemm_bt_bias(
    const void* __restrict__ Av, const void* __restrict__ Btv,
    const void* __restrict__ biasv, void* __restrict__ Cv,
    int M, int N, int K, const int* __restrict__ flagp,
    int a_flagged, int b_flagged, int out_flagged) {
    __shared__ __align__(16) u16 lA[128 * 32];
    __shared__ __align__(16) u16 lB[128 * 32];
    const int fl = flagp[0];
    const int fa = a_flagged ? fl : 1;
    const int fb = b_flagged ? fl : 1;
    const int fo = out_flagged ? fl : 1;

    const int tid = threadIdx.x;
    const int w = __builtin_amdgcn_readfirstlane(tid >> 6);
    const int lane = tid & 63;
    const int quad = lane >> 4;
    const int l16 = lane & 15;
    const int bm = blockIdx.y * 128;
    const int bn = blockIdx.x * 128;
    const int wm = (w >> 1) * 64;
    const int wn = (w & 1) * 64;

    f32x4 acc[4][4];
#pragma unroll
    for (int i = 0; i < 4; ++i)
#pragma unroll
        for (int j = 0; j < 4; ++j) acc[i][j] = {0.f, 0.f, 0.f, 0.f};

    const int kiters = K >> 5;
    for (int kk = 0; kk < kiters; ++kk) {
        __syncthreads();  // previous tile fully consumed
        if (fa) {
            const u16* A = (const u16*)Av;
#pragma unroll
            for (int c = 0; c < 2; ++c) {
                const int chunk = w * 2 + c;
                const int off = chunk * 1024 + lane * 16;  // byte off in 8KB tile
                const int m = off >> 6;
                const int kb = off & 63;
                gld_lds16((const char*)(A + (size_t)(bm + m) * K + kk * 32) + kb,
                          (char*)lA + chunk * 1024);
            }
        } else {
            const float* Af = (const float*)Av;
#pragma unroll
            for (int c = 0; c < 2; ++c) {
                const int e = (w * 2 + c) * 512 + lane * 8;  // element off in tile
                const int m = e >> 5, kc = e & 31;
                const float* ga = Af + (size_t)(bm + m) * K + kk * 32 + kc;
                const f32x4 v0 = *(const f32x4*)ga;
                const f32x4 v1 = *(const f32x4*)(ga + 4);
                short8v o;
#pragma unroll
                for (int q = 0; q < 4; ++q) o[q] = (short)f2bf(v0[q]);
#pragma unroll
                for (int q = 0; q < 4; ++q) o[4 + q] = (short)f2bf(v1[q]);
                *(short8v*)&lA[m * 32 + kc] = o;
            }
        }
        if (fb) {
            const u16* Bt = (const u16*)Btv;
#pragma unroll
            for (int c = 0; c < 2; ++c) {
                const int chunk = w * 2 + c;
                const int off = chunk * 1024 + lane * 16;
                const int m = off >> 6;
                const int kb = off & 63;
                gld_lds16((const char*)(Bt + (size_t)(bn + m) * K + kk * 32) + kb,
                          (char*)lB + chunk * 1024);
            }
        } else {
            const float* Btf = (const float*)Btv;
#pragma unroll
            for (int c = 0; c < 2; ++c) {
                const int e = (w * 2 + c) * 512 + lane * 8;
                const int m = e >> 5, kc = e & 31;
                const float* ga = Btf + (size_t)(bn + m) * K + kk * 32 + kc;
                const f32x4 v0 = *(const f32x4*)ga;
                const f32x4 v1 = *(const f32x4*)(ga + 4);
                short8v o;
#pragma unroll
                for (int q = 0; q < 4; ++q) o[q] = (short)f2bf(v0[q]);
#pragma unroll
                for (int q = 0; q < 4; ++q) o[4 + q] = (short)f2bf(v1[q]);
                *(short8v*)&lB[m * 32 + kc] = o;
            }
        }
        __syncthreads();  // drains vmcnt (async LDS loads) + lgkm + barrier

        short8v af[4], bf[4];
#pragma unroll
        for (int t = 0; t < 4; ++t) {
            af[t] = *(const short8v*)&lA[(wm + t * 16 + l16) * 32 + quad * 8];
            bf[t] = *(const short8v*)&lB[(wn + t * 16 + l16) * 32 + quad * 8];
        }
#pragma unroll
        for (int i = 0; i < 4; ++i)
#pragma unroll
            for (int j = 0; j < 4; ++j)
                acc[i][j] = __builtin_amdgcn_mfma_f32_16x16x32_bf16(af[i], bf[j], acc[i][j], 0, 0, 0);
    }

    // epilogue: C row = quad*4+r, col = lane&15 (m89/m91-verified layout)
#pragma unroll
    for (int j = 0; j < 4; ++j) {
        const int col = bn + wn + j * 16 + l16;
        const float bv = fl ? bf2f(((const u16*)biasv)[col]) : ((const float*)biasv)[col];
#pragma unroll
        for (int i = 0; i < 4; ++i) {
            const int row0 = bm + wm + i * 16 + quad * 4;
#pragma unroll
            for (int r = 0; r < 4; ++r) {
                const float val = acc[i][j][r] + bv;
                const size_t idx = (size_t)(row0 + r) * N + col;
                if (fo) ((u16*)Cv)[idx] = f2bf(val);
                else ((float*)Cv)[idx] = val;
            }
        }
    }
}

// ---------------------------------------------------------------------------
// Fused: RoPE on q,k + reorder to (B,H,S,64)  [blocks 0..8191]
//        V -> V^T (B,H,64,S) via padded LDS   [blocks 8192..9215]
// Both roles use 256 threads; role is wave-uniform (split on blockIdx.x).
// ---------------------------------------------------------------------------
__global__ __launch_bounds__(256) void rope_vt(
    const u16* __restrict__ qkv, u16* __restrict__ qws, u16* __restrict__ kws,
    u16* __restrict__ vTo) {
    __shared__ u16 tile[64 * 65];
    if (blockIdx.x < 8192) {
        const int idx = blockIdx.x * 256 + threadIdx.x;  // B*S*H*32 = 2^21
        const int i = idx & 31;
        const int h = (idx >> 5) & 15;
        const int s = (idx >> 9) & 2047;
        const int b = idx >> 20;
        const u16* src = qkv + ((size_t)(b * S_LEN + s)) * (3 * DM) + h * HD + 2 * i;
        const u32 qp = *(const u32*)(src);
        const u32 kp = *(const u32*)(src + DM);
        const float q1 = bf2f((u16)qp), q2 = bf2f((u16)(qp >> 16));
        const float k1 = bf2f((u16)kp), k2 = bf2f((u16)(kp >> 16));
        const float freq = expf(-(float)(2 * i) * 0.14391156831212787f);  // 10000^(-2i/64)
        const float th = (float)s * freq;
        float sn, cs;
        sincosf(th, &sn, &cs);
        const float oq1 = q1 * cs - q2 * sn, oq2 = q1 * sn + q2 * cs;
        const float ok1 = k1 * cs - k2 * sn, ok2 = k1 * sn + k2 * cs;
        const size_t dst = ((size_t)((b * NH + h) * S_LEN + s)) * HD + 2 * i;
        *(u32*)(qws + dst) = (u32)f2bf(oq1) | ((u32)f2bf(oq2) << 16);
        *(u32*)(kws + dst) = (u32)f2bf(ok1) | ((u32)f2bf(ok2) << 16);
    } else {
        const int bid = blockIdx.x - 8192;  // 1024 blocks
        const int s0 = (bid & 31) * 64;
        const int h = (bid >> 5) & 15, b = bid >> 9;
        const int t = threadIdx.x;
#pragma unroll
        for (int it = 0; it < 16; ++it) {
            const int e = t + 256 * it;
            const int sl = e >> 6, d = e & 63;
            tile[sl * 65 + d] =
                qkv[((size_t)(b * S_LEN + s0 + sl)) * (3 * DM) + 2 * DM + h * HD + d];
        }
        __syncthreads();
#pragma unroll
        for (int it = 0; it < 16; ++it) {
            const int e = t + 256 * it;
            const int d = e >> 6, sl = e & 63;
            vTo[((size_t)((b * NH + h) * HD + d)) * S_LEN + s0 + sl] = tile[sl * 65 + d];
        }
    }
}

// ---------------------------------------------------------------------------
// Flash attention, swapped-operand, Sk=64, XCD-pinned, contiguous-32-row
// waves, longest-first + K/V LDS DOUBLE-BUFFERED via global_load_lds.
//
// Grid: 1-D, 1024 blocks of 128 threads (2 waves). id = qbr*32 + g, g=(b,h)
// low 5 bits -> XCD pin (R3-verified: FETCH 74.6 -> 12.3 MB). qb = 31-qbr.
//
// Per kt: __syncthreads() (drains previous tile's DMA via vmcnt(0) + joins
// waves), then issue next tile's 8 gld_lds DMAs into the other buffer --
// async DMA cannot be sunk by the compiler (R2 failure mode), so the ~300-600
// cycle load latency hides under a full iteration of QK+softmax+PV compute.
//
// LDS K/V tiles are stored SWIZZLED (both-sides rule, m173/m201): linear
// 128B-row layout is a 16-way bank conflict on b128 fragment reads; instead
// the global SOURCE address pre-swizzles col16 ^= (row&7) and the reads XOR
// the linear offset with ((l16&7)<<4) -> 2-way spread (free). The gld_lds
// dest stays linear (HW requirement).
//
// P staging: halves serialized (sm0 -> PV0 -> sm1 -> PV1) so one 16-row
// P buffer per wave suffices (stride-36 u32 rows, R4-verified banking).
// LDS/block = 32KB (K,V x2 bufs) + 4.6KB (P) = 37.4KB -> 4 blocks/CU.
// ---------------------------------------------------------------------------
__global__ __launch_bounds__(128, 2) void attn_kernel(
    const u16* __restrict__ qws, const u16* __restrict__ kws,
    const u16* __restrict__ vT, u16* __restrict__ ows) {
    __shared__ __align__(16) u16 kvt[2][2][64 * 64];  // [buf][0=K,1=V] 32 KB
    __shared__ __align__(16) u32 pl32[2][16 * 36];    // per-wave P, 4.6 KB
    const int t = threadIdx.x;
    const int w = __builtin_amdgcn_readfirstlane(t >> 6);
    const int lane = t & 63;
    const int quad = lane >> 4;
    const int l16 = lane & 15;

    const int id = blockIdx.x;
    const int g = id & 31;          // (b,h) group - pinned to XCD g%8
    const int qb = 31 - (id >> 5);  // longest-first
    const int h = g & 15, b = g >> 4;
    const int q0 = qb * 64 + w * 32;  // wave's first q-row

    const size_t bh = (size_t)(b * NH + h);
    const u16* qbp = qws + bh * (size_t)S_LEN * HD;
    const u16* kb = kws + bh * (size_t)S_LEN * HD;
    const u16* vb = vT + bh * (size_t)HD * S_LEN;

    // staging geometry: chunk = w*4+c covers 8 rows (1KB); lane writes 16B.
    const int srow = lane >> 3;                 // row within chunk (0..7)
    const int scol = ((lane & 7) ^ srow) << 4;  // pre-swizzled byte col
    const int xorb = (l16 & 7) << 4;            // read-side swizzle XOR

    short8v qf[2][2];  // [half][hf]
#pragma unroll
    for (int hh = 0; hh < 2; ++hh)
#pragma unroll
        for (int hf = 0; hf < 2; ++hf)
            qf[hh][hf] =
                *(const short8v*)(qbp + (size_t)(q0 + hh * 16 + l16) * HD + hf * 32 + quad * 8);

    f32x4 oaccT[2][4];  // [half][d-frag]: row = d (quad*4+r), col = q (l16)
    float mrow[2], lrow[2];
#pragma unroll
    for (int hh = 0; hh < 2; ++hh) {
#pragma unroll
        for (int d = 0; d < 4; ++d) oaccT[hh][d] = {0.f, 0.f, 0.f, 0.f};
        mrow[hh] = -__builtin_inff();
        lrow[hh] = 0.f;
    }

    // prologue: stage tile 0 into buf 0
#pragma unroll
    for (int c = 0; c < 4; ++c) {
        const int chunk = w * 4 + c;
        const int row = chunk * 8 + srow;
        gld_lds16(kb + (size_t)row * HD + (scol >> 1), (char*)&kvt[0][0][0] + chunk * 1024);
        gld_lds16(vb + (size_t)row * S_LEN + (scol >> 1), (char*)&kvt[0][1][0] + chunk * 1024);
    }

    int cur = 0;
    for (int kt = 0; kt <= qb; ++kt) {
        __syncthreads();  // buf[cur] DMA complete; both waves done with buf[cur^1]
        if (kt < qb) {    // prefetch next tile into the free buffer
#pragma unroll
            for (int c = 0; c < 4; ++c) {
                const int chunk = w * 4 + c;
                const int row = chunk * 8 + srow;
                gld_lds16(kb + (size_t)((kt + 1) * 64 + row) * HD + (scol >> 1),
                          (char*)&kvt[cur ^ 1][0][0] + chunk * 1024);
                gld_lds16(vb + (size_t)row * S_LEN + (kt + 1) * 64 + (scol >> 1),
                          (char*)&kvt[cur ^ 1][1][0] + chunk * 1024);
            }
        }
        const char* Kb = (const char*)&kvt[cur][0][0];
        const char* Vb = (const char*)&kvt[cur][1][0];

#pragma unroll
        for (int hh = 0; hh < 2; ++hh) {
            // S^T sub-tiles: row = k (quad*4+r within sub), col = q (l16)
            f32x4 s[4];
#pragma unroll
            for (int sub = 0; sub < 4; ++sub) {
                const int lin = (sub * 16 + l16) * 128 + quad * 16;
                const short8v k0 = *(const short8v*)(Kb + (lin ^ xorb));
                const short8v k1 = *(const short8v*)(Kb + ((lin + 64) ^ xorb));
                f32x4 a = {0.f, 0.f, 0.f, 0.f};
                a = __builtin_amdgcn_mfma_f32_16x16x32_bf16(k0, qf[hh][0], a, 0, 0, 0);
                a = __builtin_amdgcn_mfma_f32_16x16x32_bf16(k1, qf[hh][1], a, 0, 0, 0);
                s[sub] = a;
            }
            float sv[16];
#pragma unroll
            for (int sub = 0; sub < 4; ++sub)
#pragma unroll
                for (int r = 0; r < 4; ++r) sv[sub * 4 + r] = s[sub][r] * 0.125f;
            if (kt == qb) {  // single masked tile: k > q -> -inf
                const int qg = q0 + hh * 16 + l16;
#pragma unroll
                for (int sub = 0; sub < 4; ++sub)
#pragma unroll
                    for (int r = 0; r < 4; ++r)
                        if (kt * 64 + sub * 16 + quad * 4 + r > qg)
                            sv[sub * 4 + r] = -__builtin_inff();
            }
            // per-q-row max: 15 in-lane (tree) + 2 cross-lane
            float a0 = fmaxf(sv[0], sv[1]), a1 = fmaxf(sv[2], sv[3]);
            float a2 = fmaxf(sv[4], sv[5]), a3 = fmaxf(sv[6], sv[7]);
            float a4 = fmaxf(sv[8], sv[9]), a5 = fmaxf(sv[10], sv[11]);
            float a6 = fmaxf(sv[12], sv[13]), a7 = fmaxf(sv[14], sv[15]);
            a0 = fmaxf(a0, a1); a2 = fmaxf(a2, a3);
            a4 = fmaxf(a4, a5); a6 = fmaxf(a6, a7);
            a0 = fmaxf(a0, a2); a4 = fmaxf(a4, a6);
            float mx = fmaxf(a0, a4);
            mx = fmaxf(mx, __shfl_xor(mx, 16));
            mx = fmaxf(mx, __shfl_xor(mx, 32));
            const float mnew = fmaxf(mrow[hh], mx);
            const float alpha = __expf(mrow[hh] - mnew);
            mrow[hh] = mnew;
            float p[16];
#pragma unroll
            for (int i = 0; i < 16; ++i) p[i] = __expf(sv[i] - mnew);
            float b0 = p[0] + p[1], b1 = p[2] + p[3], b2 = p[4] + p[5], b3 = p[6] + p[7];
            float b4 = p[8] + p[9], b5 = p[10] + p[11], b6 = p[12] + p[13], b7 = p[14] + p[15];
            b0 += b1; b2 += b3; b4 += b5; b6 += b7;
            b0 += b2; b4 += b6;
            float ps = b0 + b4;
            ps += __shfl_xor(ps, 16);
            ps += __shfl_xor(ps, 32);
            lrow[hh] = lrow[hh] * alpha + ps;
#pragma unroll
            for (int d = 0; d < 4; ++d) oaccT[hh][d] *= alpha;
            // pack P[q=l16][k] to bf16 pairs; 4x b64 writes (stride-36 rows)
            u32* prow = &pl32[w][l16 * 36];
#pragma unroll
            for (int sub = 0; sub < 4; ++sub) {
                u32x2 pw;
                pw.x = (u32)f2bf(p[sub * 4 + 0]) | ((u32)f2bf(p[sub * 4 + 1]) << 16);
                pw.y = (u32)f2bf(p[sub * 4 + 2]) | ((u32)f2bf(p[sub * 4 + 3]) << 16);
                *(u32x2*)&prow[sub * 8 + quad * 2] = pw;  // keys sub*16+quad*4..+3
            }
            __threadfence_block();  // wave-private LDS; DS ops in-order per wave
            // PV for this half: B-frag reads P[q][c2*32 + quad*8 .. +7]
#pragma unroll
            for (int c2 = 0; c2 < 2; ++c2) {
                const short8v pf = *(const short8v*)&pl32[w][l16 * 36 + c2 * 16 + quad * 4];
#pragma unroll
                for (int d = 0; d < 4; ++d) {
                    const int lin = (d * 16 + l16) * 128 + c2 * 64 + quad * 16;
                    const short8v vfd = *(const short8v*)(Vb + (lin ^ xorb));
                    oaccT[hh][d] =
                        __builtin_amdgcn_mfma_f32_16x16x32_bf16(vfd, pf, oaccT[hh][d], 0, 0, 0);
                }
            }
        }
        cur ^= 1;
    }

    // epilogue: O[q][d] with q = q0+hh*16+l16, d = df*16+quad*4+r -> 8B stores
#pragma unroll
    for (int hh = 0; hh < 2; ++hh) {
        const float inv = 1.0f / lrow[hh];
        const size_t rowbase = ((size_t)(b * S_LEN + q0 + hh * 16 + l16)) * DM + h * HD;
#pragma unroll
        for (int df = 0; df < 4; ++df) {
            const int d0 = df * 16 + quad * 4;
            u32x2 ov;
            ov.x = (u32)f2bf(oaccT[hh][df][0] * inv) | ((u32)f2bf(oaccT[hh][df][1] * inv) << 16);
            ov.y = (u32)f2bf(oaccT[hh][df][2] * inv) | ((u32)f2bf(oaccT[hh][df][3] * inv) << 16);
            *(u32x2*)(ows + rowbase + d0) = ov;
        }
    }
}

extern "C" void kernel_launch(void* const* d_in, const int* in_sizes, int n_in,
                              void* d_out, int out_size, void* d_ws, size_t ws_size,
                              hipStream_t stream) {
    const void* x = d_in[0];
    const void* w_qkv = d_in[1];
    const void* b_qkv = d_in[2];
    const void* w_out = d_in[3];
    const void* b_out = d_in[4];

    int* flag = (int*)d_ws;
    u16* qkv = (u16*)d_ws + 8;                      // 16B-aligned, 24 MB
    u16* qws = qkv + (size_t)TOK * 3 * DM;          // (B,H,S,64), 8 MB
    u16* kws = qws + (size_t)NB * NH * S_LEN * HD;  // 8 MB
    u16* vT = kws + (size_t)NB * NH * S_LEN * HD;   // (B,H,64,S), 8 MB
    u16* woutb = vT + (size_t)NB * NH * HD * S_LEN; // 2 MB
    u16* ows = qkv;    // alias: qkv dead after rope_vt
    u16* xb = qws;     // alias: xb dead before rope_vt writes qws
    u16* wqkvb = kws;  // alias: wqkvb dead before rope_vt writes kws

    detect_dtype<<<1, 256, 0, stream>>>((const u32*)x, flag);
    convert_all<<<(XCH + WQCH + WOCH) / 256, 256, 0, stream>>>(
        x, w_qkv, w_out, xb, wqkvb, woutb, flag);

    gemm_bt_bias<<<dim3(3 * DM / 128, TOK / 128), 256, 0, stream>>>(
        xb, wqkvb, b_qkv, qkv, TOK, 3 * DM, DM, flag, 0, 0, 0);
    rope_vt<<<8192 + 1024, 256, 0, stream>>>(qkv, qws, kws, vT);
    // 1-D grid: id = qbr*32 + g, g=(b,h). 1024 blocks x 128 threads.
    attn_kernel<<<dim3(32 * 32), 128, 0, stream>>>(qws, kws, vT, ows);
    gemm_bt_bias<<<dim3(DM / 128, TOK / 128), 256, 0, stream>>>(
        ows, woutb, b_out, d_out, TOK, DM, DM, flag, 0, 0, 1);
}

// Round 6
// 218.314 us; speedup vs baseline: 1.9202x; 1.1612x over previous
//
#include <hip/hip_runtime.h>
#include <stdint.h>

#define S_LEN 2048
#define NH 16
#define DM 1024
#define HD 64
#define NB 2
#define TOK (NB * S_LEN)  // 4096

typedef __attribute__((ext_vector_type(8))) short short8v;  // 8 bf16 = 4 VGPR
typedef __attribute__((ext_vector_type(4))) float f32x4;
typedef __attribute__((ext_vector_type(2))) unsigned int u32x2;
typedef unsigned short u16;
typedef unsigned int u32;

__device__ __forceinline__ float bf2f(u16 u) {
    u32 x = ((u32)u) << 16;
    return __builtin_bit_cast(float, x);
}
__device__ __forceinline__ u16 f2bf(float f) {  // RNE
    u32 u = __builtin_bit_cast(u32, f);
    return (u16)((u + 0x7FFFu + ((u >> 16) & 1u)) >> 16);
}
// pack 2 floats -> 2 bf16 in one instr (RNE); lo -> bits 15:0
__device__ __forceinline__ u32 cvtpk(float lo, float hi) {
    u32 r;
    asm("v_cvt_pk_bf16_f32 %0, %1, %2" : "=v"(r) : "v"(lo), "v"(hi));
    return r;
}

// async global->LDS, 16B per lane. LDS dest = wave-uniform base + lane*16 (HW).
__device__ __forceinline__ void gld_lds16(const void* g, void* lds_base_uniform) {
    auto gp = (const __attribute__((address_space(1))) u32*)(uintptr_t)g;
    auto lp = (__attribute__((address_space(3))) u32*)(uintptr_t)(u32)(uintptr_t)lds_base_uniform;
    __builtin_amdgcn_global_load_lds(gp, lp, 16, 0, 0);
}

// ---------------------------------------------------------------------------
// dtype sniffer: flag=1 if x is bf16, 0 if fp32.
// ---------------------------------------------------------------------------
__global__ void detect_dtype(const u32* __restrict__ xw, int* __restrict__ flag) {
    __shared__ int cnt[4];
    const int t = threadIdx.x;
    int c = 0;
#pragma unroll
    for (int j = 0; j < 16; ++j) {
        const u32 wd = xw[(t * 16 + j) * 64];
        const u32 e = (wd >> 7) & 0xFF;
        c += (e >= 0x58 && e <= 0x98) ? 1 : 0;
    }
#pragma unroll
    for (int off = 1; off < 64; off <<= 1) c += __shfl_xor(c, off);
    if ((t & 63) == 0) cnt[t >> 6] = c;
    __syncthreads();
    if (t == 0) flag[0] = (cnt[0] + cnt[1] + cnt[2] + cnt[3] >= 2600) ? 1 : 0;
}

// ---------------------------------------------------------------------------
// Fused fp32 -> bf16 conversion of x, w_qkv, w_out (copy-through when bf16).
// ---------------------------------------------------------------------------
#define XCH (TOK * DM / 8)           // 524288
#define WQCH (3 * DM * DM / 8)       // 393216
#define WOCH (DM * DM / 8)           // 131072
__global__ __launch_bounds__(256) void convert_all(
    const void* __restrict__ xs, const void* __restrict__ wqs, const void* __restrict__ wos,
    u16* __restrict__ xd, u16* __restrict__ wqd, u16* __restrict__ wod,
    const int* __restrict__ flagp) {
    int i = blockIdx.x * 256 + threadIdx.x;
    const void* src;
    u16* dst;
    if (i < XCH) {
        src = xs; dst = xd;
    } else if (i < XCH + WQCH) {
        src = wqs; dst = wqd; i -= XCH;
    } else {
        src = wos; dst = wod; i -= XCH + WQCH;
    }
    if (flagp[0]) {
        ((short8v*)dst)[i] = ((const short8v*)src)[i];
    } else {
        const f32x4 v0 = ((const f32x4*)src)[2 * i];
        const f32x4 v1 = ((const f32x4*)src)[2 * i + 1];
        short8v o;
#pragma unroll
        for (int q = 0; q < 4; ++q) o[q] = (short)f2bf(v0[q]);
#pragma unroll
        for (int q = 0; q < 4; ++q) o[4 + q] = (short)f2bf(v1[q]);
        ((short8v*)dst)[i] = o;
    }
}

// ---------------------------------------------------------------------------
// C[m,n] = sum_k A[m,k]*Bt[n,k] + bias[n]; bf16 inputs (post-convert), fp32
// accum. 128x128 tile, BK=32, LDS DOUBLE-BUFFERED gld_lds staging: stage
// kk+1 right after the barrier, compute kk from the other buffer -> DMA
// latency hides under a full compute phase (R5-attn-proven pattern).
// ---------------------------------------------------------------------------
__global__ __launch_bounds__(256) void gemm_bt_bias(
    const u16* __restrict__ A, const u16* __restrict__ Bt,
    const void* __restrict__ biasv, void* __restrict__ Cv,
    int M, int N, int K, const int* __restrict__ flagp, int out_flagged) {
    __shared__ __align__(16) u16 lA[2][128 * 32];
    __shared__ __align__(16) u16 lB[2][128 * 32];
    const int fl = flagp[0];
    const int fo = out_flagged ? fl : 1;

    const int tid = threadIdx.x;
    const int w = __builtin_amdgcn_readfirstlane(tid >> 6);
    const int lane = tid & 63;
    const int quad = lane >> 4;
    const int l16 = lane & 15;
    const int bm = blockIdx.y * 128;
    const int bn = blockIdx.x * 128;
    const int wm = (w >> 1) * 64;
    const int wn = (w & 1) * 64;

    f32x4 acc[4][4];
#pragma unroll
    for (int i = 0; i < 4; ++i)
#pragma unroll
        for (int j = 0; j < 4; ++j) acc[i][j] = {0.f, 0.f, 0.f, 0.f};

    const int kiters = K >> 5;
    // stage tile kk into buf: chunk = w*2+c (1KB each), lane writes 16B
#define GEMM_STAGE(kk, buf)                                                            \
    {                                                                                  \
        _Pragma("unroll") for (int c = 0; c < 2; ++c) {                                \
            const int chunk = w * 2 + c;                                               \
            const int off = chunk * 1024 + lane * 16;                                  \
            const int m = off >> 6;                                                    \
            const int kb_ = off & 63;                                                  \
            gld_lds16((const char*)(A + (size_t)(bm + m) * K + (kk) * 32) + kb_,       \
                      (char*)&lA[buf][0] + chunk * 1024);                              \
            gld_lds16((const char*)(Bt + (size_t)(bn + m) * K + (kk) * 32) + kb_,      \
                      (char*)&lB[buf][0] + chunk * 1024);                              \
        }                                                                              \
    }

    GEMM_STAGE(0, 0);
    int cur = 0;
    for (int kk = 0; kk < kiters; ++kk) {
        __syncthreads();  // drains buf[cur] DMA; all waves done reading buf[cur^1]
        if (kk + 1 < kiters) GEMM_STAGE(kk + 1, cur ^ 1);

        short8v af[4], bf[4];
#pragma unroll
        for (int t = 0; t < 4; ++t) {
            af[t] = *(const short8v*)&lA[cur][(wm + t * 16 + l16) * 32 + quad * 8];
            bf[t] = *(const short8v*)&lB[cur][(wn + t * 16 + l16) * 32 + quad * 8];
        }
#pragma unroll
        for (int i = 0; i < 4; ++i)
#pragma unroll
            for (int j = 0; j < 4; ++j)
                acc[i][j] = __builtin_amdgcn_mfma_f32_16x16x32_bf16(af[i], bf[j], acc[i][j], 0, 0, 0);
        cur ^= 1;
    }
#undef GEMM_STAGE

    // epilogue: C row = quad*4+r, col = lane&15
#pragma unroll
    for (int j = 0; j < 4; ++j) {
        const int col = bn + wn + j * 16 + l16;
        const float bv = fl ? bf2f(((const u16*)biasv)[col]) : ((const float*)biasv)[col];
#pragma unroll
        for (int i = 0; i < 4; ++i) {
            const int row0 = bm + wm + i * 16 + quad * 4;
#pragma unroll
            for (int r = 0; r < 4; ++r) {
                const float val = acc[i][j][r] + bv;
                const size_t idx = (size_t)(row0 + r) * N + col;
                if (fo) ((u16*)Cv)[idx] = f2bf(val);
                else ((float*)Cv)[idx] = val;
            }
        }
    }
}

// ---------------------------------------------------------------------------
// Fused: RoPE on q,k + reorder to (B,H,S,64)  [blocks 0..8191]
//        V -> V^T (B,H,64,S) via padded LDS   [blocks 8192..9215]
// ---------------------------------------------------------------------------
__global__ __launch_bounds__(256) void rope_vt(
    const u16* __restrict__ qkv, u16* __restrict__ qws, u16* __restrict__ kws,
    u16* __restrict__ vTo) {
    __shared__ u16 tile[64 * 65];
    if (blockIdx.x < 8192) {
        const int idx = blockIdx.x * 256 + threadIdx.x;
        const int i = idx & 31;
        const int h = (idx >> 5) & 15;
        const int s = (idx >> 9) & 2047;
        const int b = idx >> 20;
        const u16* src = qkv + ((size_t)(b * S_LEN + s)) * (3 * DM) + h * HD + 2 * i;
        const u32 qp = *(const u32*)(src);
        const u32 kp = *(const u32*)(src + DM);
        const float q1 = bf2f((u16)qp), q2 = bf2f((u16)(qp >> 16));
        const float k1 = bf2f((u16)kp), k2 = bf2f((u16)(kp >> 16));
        const float freq = expf(-(float)(2 * i) * 0.14391156831212787f);
        const float th = (float)s * freq;
        float sn, cs;
        sincosf(th, &sn, &cs);
        const float oq1 = q1 * cs - q2 * sn, oq2 = q1 * sn + q2 * cs;
        const float ok1 = k1 * cs - k2 * sn, ok2 = k1 * sn + k2 * cs;
        const size_t dst = ((size_t)((b * NH + h) * S_LEN + s)) * HD + 2 * i;
        *(u32*)(qws + dst) = (u32)f2bf(oq1) | ((u32)f2bf(oq2) << 16);
        *(u32*)(kws + dst) = (u32)f2bf(ok1) | ((u32)f2bf(ok2) << 16);
    } else {
        const int bid = blockIdx.x - 8192;
        const int s0 = (bid & 31) * 64;
        const int h = (bid >> 5) & 15, b = bid >> 9;
        const int t = threadIdx.x;
#pragma unroll
        for (int it = 0; it < 16; ++it) {
            const int e = t + 256 * it;
            const int sl = e >> 6, d = e & 63;
            tile[sl * 65 + d] =
                qkv[((size_t)(b * S_LEN + s0 + sl)) * (3 * DM) + 2 * DM + h * HD + d];
        }
        __syncthreads();
#pragma unroll
        for (int it = 0; it < 16; ++it) {
            const int e = t + 256 * it;
            const int d = e >> 6, sl = e & 63;
            vTo[((size_t)((b * NH + h) * HD + d)) * S_LEN + s0 + sl] = tile[sl * 65 + d];
        }
    }
}

// ---------------------------------------------------------------------------
// Flash attention. 256-thread blocks = 4 waves x 16 q-rows (64 rows/block).
// Grid 1024: id = qbr*32 + g, g=(b,h) low 5 bits -> XCD pin (R3: FETCH
// 74.6 -> 12.3 MB); qb = 31-qbr (longest-first).
//
// Pipeline per kt (counted-vmcnt, T3/T4):
//   __syncthreads()              // drains K[kt] DMA (issued last iter)
//   issue V[kt] DMA (2/thread)   // into single V buffer
//   issue K[kt+1] DMA (2/thread) // into other K buffer - STAYS IN FLIGHT
//   QK (LDS, swizzled) + softmax + cvt_pk pack -> P (lgkm-only fence)
//   s_waitcnt vmcnt(2)           // waits V only, K[kt+1] still in flight
//   s_barrier                    // all threads' V staged
//   PV (LDS, swizzled)
// No mid-iteration vmcnt(0) drain (R5's __threadfence_block bug fixed).
//
// K/V LDS swizzle both-sides (m173/m201): source col16 ^= row&7, read
// offset ^= (l16&7)<<4; gld_lds dest stays linear. LDS = 16K(Kx2) + 8K(V)
// + 9K(P) = 33.8KB -> 4 blocks/CU; launch_bounds(256,4) -> 16 waves/CU.
// ---------------------------------------------------------------------------
__global__ __launch_bounds__(256, 4) void attn_kernel(
    const u16* __restrict__ qws, const u16* __restrict__ kws,
    const u16* __restrict__ vT, u16* __restrict__ ows) {
    __shared__ __align__(16) u16 kl[2][64 * 64];    // K dbuf, 16 KB
    __shared__ __align__(16) u16 vl[64 * 64];       // V single, 8 KB
    __shared__ __align__(16) u32 pl32[4][16 * 36];  // per-wave P, 9216 B
    const int t = threadIdx.x;
    const int w = __builtin_amdgcn_readfirstlane(t >> 6);
    const int lane = t & 63;
    const int quad = lane >> 4;
    const int l16 = lane & 15;

    const int id = blockIdx.x;
    const int g = id & 31;          // (b,h) -> XCD pin g%8
    const int qb = 31 - (id >> 5);  // longest-first
    const int h = g & 15, b = g >> 4;
    const int q0 = qb * 64 + w * 16;  // wave's 16 q-rows

    const size_t bh = (size_t)(b * NH + h);
    const u16* qbp = qws + bh * (size_t)S_LEN * HD;
    const u16* kb = kws + bh * (size_t)S_LEN * HD;
    const u16* vb = vT + bh * (size_t)HD * S_LEN;

    // staging geometry: wave w stages rows [w*8+s*32 .. +7], lane -> 16B
    const int r0 = lane >> 3;                // row within 8-row group
    const int srcc = (lane & 7) ^ r0;        // pre-swizzled col16
    const int xorb = (l16 & 7) << 4;         // read-side swizzle XOR

    short8v qf[2];
#pragma unroll
    for (int hf = 0; hf < 2; ++hf)
        qf[hf] = *(const short8v*)(qbp + (size_t)(q0 + l16) * HD + hf * 32 + quad * 8);

    f32x4 oaccT[4];  // row = d (quad*4+r), col = q (l16)
#pragma unroll
    for (int d = 0; d < 4; ++d) oaccT[d] = {0.f, 0.f, 0.f, 0.f};
    float mrow = -__builtin_inff();
    float lrow = 0.f;

    // prologue: stage K[0]
#pragma unroll
    for (int s = 0; s < 2; ++s) {
        const int row = w * 8 + s * 32 + r0;
        gld_lds16(kb + (size_t)row * HD + srcc * 8, (char*)&kl[0][0] + w * 1024 + s * 4096);
    }

    int cur = 0;
    for (int kt = 0; kt <= qb; ++kt) {
        __syncthreads();  // K[kt] staged by all; V free; kl[cur^1] free
        // issue V[kt] FIRST (oldest in vm queue), then K[kt+1]
#pragma unroll
        for (int s = 0; s < 2; ++s) {
            const int row = w * 8 + s * 32 + r0;
            gld_lds16(vb + (size_t)row * S_LEN + kt * 64 + srcc * 8,
                      (char*)&vl[0] + w * 1024 + s * 4096);
        }
        if (kt < qb) {
#pragma unroll
            for (int s = 0; s < 2; ++s) {
                const int row = w * 8 + s * 32 + r0;
                gld_lds16(kb + (size_t)((kt + 1) * 64 + row) * HD + srcc * 8,
                          (char*)&kl[cur ^ 1][0] + w * 1024 + s * 4096);
            }
        }
        const char* Kb = (const char*)&kl[cur][0];

        // S^T sub-tiles: row = k (quad*4+r within sub), col = q (l16)
        f32x4 s4[4];
        __builtin_amdgcn_s_setprio(1);
#pragma unroll
        for (int sub = 0; sub < 4; ++sub) {
            const int lin = (sub * 16 + l16) * 128 + quad * 16;
            const short8v k0 = *(const short8v*)(Kb + (lin ^ xorb));
            const short8v k1 = *(const short8v*)(Kb + ((lin + 64) ^ xorb));
            f32x4 a = {0.f, 0.f, 0.f, 0.f};
            a = __builtin_amdgcn_mfma_f32_16x16x32_bf16(k0, qf[0], a, 0, 0, 0);
            a = __builtin_amdgcn_mfma_f32_16x16x32_bf16(k1, qf[1], a, 0, 0, 0);
            s4[sub] = a;
        }
        __builtin_amdgcn_s_setprio(0);
        float sv[16];
#pragma unroll
        for (int sub = 0; sub < 4; ++sub)
#pragma unroll
            for (int r = 0; r < 4; ++r) sv[sub * 4 + r] = s4[sub][r] * 0.125f;
        if (kt == qb) {  // masked diagonal tile: k > q -> -inf
            const int qloc = w * 16 + l16;
#pragma unroll
            for (int sub = 0; sub < 4; ++sub)
#pragma unroll
                for (int r = 0; r < 4; ++r)
                    if (sub * 16 + quad * 4 + r > qloc) sv[sub * 4 + r] = -__builtin_inff();
        }
        // per-q-row max: 15 in-lane (tree) + 2 cross-lane
        float a0 = fmaxf(sv[0], sv[1]), a1 = fmaxf(sv[2], sv[3]);
        float a2 = fmaxf(sv[4], sv[5]), a3 = fmaxf(sv[6], sv[7]);
        float a4 = fmaxf(sv[8], sv[9]), a5 = fmaxf(sv[10], sv[11]);
        float a6 = fmaxf(sv[12], sv[13]), a7 = fmaxf(sv[14], sv[15]);
        a0 = fmaxf(a0, a1); a2 = fmaxf(a2, a3);
        a4 = fmaxf(a4, a5); a6 = fmaxf(a6, a7);
        a0 = fmaxf(a0, a2); a4 = fmaxf(a4, a6);
        float mx = fmaxf(a0, a4);
        mx = fmaxf(mx, __shfl_xor(mx, 16));
        mx = fmaxf(mx, __shfl_xor(mx, 32));
        const float mnew = fmaxf(mrow, mx);
        const float alpha = __expf(mrow - mnew);
        mrow = mnew;
        float p[16];
#pragma unroll
        for (int i = 0; i < 16; ++i) p[i] = __expf(sv[i] - mnew);
        float b0 = p[0] + p[1], b1 = p[2] + p[3], b2 = p[4] + p[5], b3 = p[6] + p[7];
        float b4 = p[8] + p[9], b5 = p[10] + p[11], b6 = p[12] + p[13], b7 = p[14] + p[15];
        b0 += b1; b2 += b3; b4 += b5; b6 += b7;
        b0 += b2; b4 += b6;
        float ps = b0 + b4;
        ps += __shfl_xor(ps, 16);
        ps += __shfl_xor(ps, 32);
        lrow = lrow * alpha + ps;
#pragma unroll
        for (int d = 0; d < 4; ++d) oaccT[d] *= alpha;
        // pack P[q=l16][k] via cvt_pk; 4x b64 writes (stride-36 rows)
        u32* prow = &pl32[w][l16 * 36];
#pragma unroll
        for (int sub = 0; sub < 4; ++sub) {
            u32x2 pw;
            pw.x = cvtpk(p[sub * 4 + 0], p[sub * 4 + 1]);
            pw.y = cvtpk(p[sub * 4 + 2], p[sub * 4 + 3]);
            *(u32x2*)&prow[sub * 8 + quad * 2] = pw;
        }
        asm volatile("s_waitcnt lgkmcnt(0)" ::: "memory");  // P visible (DS in-order)
        // wait own V chunks (K[kt+1] stays in flight), then join
        if (kt < qb) {
            asm volatile("s_waitcnt vmcnt(2)" ::: "memory");
        } else {
            asm volatile("s_waitcnt vmcnt(0)" ::: "memory");
        }
        __builtin_amdgcn_s_barrier();
        asm volatile("" ::: "memory");
        // PV: B-frag = P[q][c2*32 + quad*8 .. +7]; A-frag = V^T rows
        __builtin_amdgcn_s_setprio(1);
#pragma unroll
        for (int c2 = 0; c2 < 2; ++c2) {
            const short8v pf = *(const short8v*)&pl32[w][l16 * 36 + c2 * 16 + quad * 4];
#pragma unroll
            for (int d = 0; d < 4; ++d) {
                const int lin = (d * 16 + l16) * 128 + c2 * 64 + quad * 16;
                const short8v vfd = *(const short8v*)((const char*)&vl[0] + (lin ^ xorb));
                oaccT[d] = __builtin_amdgcn_mfma_f32_16x16x32_bf16(vfd, pf, oaccT[d], 0, 0, 0);
            }
        }
        __builtin_amdgcn_s_setprio(0);
        cur ^= 1;
    }

    // epilogue: O[q][d], q = q0+l16, d = df*16+quad*4+r -> 8B packed stores
    const float inv = 1.0f / lrow;
    const size_t rowbase = ((size_t)(b * S_LEN + q0 + l16)) * DM + h * HD;
#pragma unroll
    for (int df = 0; df < 4; ++df) {
        const int d0 = df * 16 + quad * 4;
        u32x2 ov;
        ov.x = cvtpk(oaccT[df][0] * inv, oaccT[df][1] * inv);
        ov.y = cvtpk(oaccT[df][2] * inv, oaccT[df][3] * inv);
        *(u32x2*)(ows + rowbase + d0) = ov;
    }
}

extern "C" void kernel_launch(void* const* d_in, const int* in_sizes, int n_in,
                              void* d_out, int out_size, void* d_ws, size_t ws_size,
                              hipStream_t stream) {
    const void* x = d_in[0];
    const void* w_qkv = d_in[1];
    const void* b_qkv = d_in[2];
    const void* w_out = d_in[3];
    const void* b_out = d_in[4];

    int* flag = (int*)d_ws;
    u16* qkv = (u16*)d_ws + 8;                      // 16B-aligned, 24 MB
    u16* qws = qkv + (size_t)TOK * 3 * DM;          // (B,H,S,64), 8 MB
    u16* kws = qws + (size_t)NB * NH * S_LEN * HD;  // 8 MB
    u16* vT = kws + (size_t)NB * NH * S_LEN * HD;   // (B,H,64,S), 8 MB
    u16* woutb = vT + (size_t)NB * NH * HD * S_LEN; // 2 MB
    u16* ows = qkv;    // alias: qkv dead after rope_vt
    u16* xb = qws;     // alias: xb dead before rope_vt writes qws
    u16* wqkvb = kws;  // alias: wqkvb dead before rope_vt writes kws

    detect_dtype<<<1, 256, 0, stream>>>((const u32*)x, flag);
    convert_all<<<(XCH + WQCH + WOCH) / 256, 256, 0, stream>>>(
        x, w_qkv, w_out, xb, wqkvb, woutb, flag);

    gemm_bt_bias<<<dim3(3 * DM / 128, TOK / 128), 256, 0, stream>>>(
        xb, wqkvb, b_qkv, qkv, TOK, 3 * DM, DM, flag, 0);
    rope_vt<<<8192 + 1024, 256, 0, stream>>>(qkv, qws, kws, vT);
    // 1-D grid: id = qbr*32 + g, g=(b,h). 1024 blocks x 256 threads.
    attn_kernel<<<dim3(32 * 32), 256, 0, stream>>>(qws, kws, vT, ows);
    gemm_bt_bias<<<dim3(DM / 128, TOK / 128), 256, 0, stream>>>(
        ows, woutb, b_out, d_out, TOK, DM, DM, flag, 1);
}

// Round 7
// 215.506 us; speedup vs baseline: 1.9452x; 1.0130x over previous
//
#include <hip/hip_runtime.h>
#include <stdint.h>

#define S_LEN 2048
#define NH 16
#define DM 1024
#define HD 64
#define NB 2
#define TOK (NB * S_LEN)  // 4096

typedef __attribute__((ext_vector_type(8))) short short8v;  // 8 bf16 = 4 VGPR
typedef __attribute__((ext_vector_type(4))) float f32x4;
typedef __attribute__((ext_vector_type(2))) unsigned int u32x2;
typedef unsigned short u16;
typedef unsigned int u32;

__device__ __forceinline__ float bf2f(u16 u) {
    u32 x = ((u32)u) << 16;
    return __builtin_bit_cast(float, x);
}
__device__ __forceinline__ u16 f2bf(float f) {  // RNE
    u32 u = __builtin_bit_cast(u32, f);
    return (u16)((u + 0x7FFFu + ((u >> 16) & 1u)) >> 16);
}
// pack 2 floats -> 2 bf16 in one instr (RNE); lo -> bits 15:0
__device__ __forceinline__ u32 cvtpk(float lo, float hi) {
    u32 r;
    asm("v_cvt_pk_bf16_f32 %0, %1, %2" : "=v"(r) : "v"(lo), "v"(hi));
    return r;
}

// async global->LDS, 16B per lane. LDS dest = wave-uniform base + lane*16 (HW).
__device__ __forceinline__ void gld_lds16(const void* g, void* lds_base_uniform) {
    auto gp = (const __attribute__((address_space(1))) u32*)(uintptr_t)g;
    auto lp = (__attribute__((address_space(3))) u32*)(uintptr_t)(u32)(uintptr_t)lds_base_uniform;
    __builtin_amdgcn_global_load_lds(gp, lp, 16, 0, 0);
}

// ---------------------------------------------------------------------------
// dtype sniffer: flag=1 if x is bf16, 0 if fp32.
// ---------------------------------------------------------------------------
__global__ void detect_dtype(const u32* __restrict__ xw, int* __restrict__ flag) {
    __shared__ int cnt[4];
    const int t = threadIdx.x;
    int c = 0;
#pragma unroll
    for (int j = 0; j < 16; ++j) {
        const u32 wd = xw[(t * 16 + j) * 64];
        const u32 e = (wd >> 7) & 0xFF;
        c += (e >= 0x58 && e <= 0x98) ? 1 : 0;
    }
#pragma unroll
    for (int off = 1; off < 64; off <<= 1) c += __shfl_xor(c, off);
    if ((t & 63) == 0) cnt[t >> 6] = c;
    __syncthreads();
    if (t == 0) flag[0] = (cnt[0] + cnt[1] + cnt[2] + cnt[3] >= 2600) ? 1 : 0;
}

// ---------------------------------------------------------------------------
// Fused fp32 -> bf16 conversion of x, w_qkv, w_out (copy-through when bf16).
// ---------------------------------------------------------------------------
#define XCH (TOK * DM / 8)           // 524288
#define WQCH (3 * DM * DM / 8)       // 393216
#define WOCH (DM * DM / 8)           // 131072
__global__ __launch_bounds__(256) void convert_all(
    const void* __restrict__ xs, const void* __restrict__ wqs, const void* __restrict__ wos,
    u16* __restrict__ xd, u16* __restrict__ wqd, u16* __restrict__ wod,
    const int* __restrict__ flagp) {
    int i = blockIdx.x * 256 + threadIdx.x;
    const void* src;
    u16* dst;
    if (i < XCH) {
        src = xs; dst = xd;
    } else if (i < XCH + WQCH) {
        src = wqs; dst = wqd; i -= XCH;
    } else {
        src = wos; dst = wod; i -= XCH + WQCH;
    }
    if (flagp[0]) {
        ((short8v*)dst)[i] = ((const short8v*)src)[i];
    } else {
        const f32x4 v0 = ((const f32x4*)src)[2 * i];
        const f32x4 v1 = ((const f32x4*)src)[2 * i + 1];
        short8v o;
#pragma unroll
        for (int q = 0; q < 4; ++q) o[q] = (short)f2bf(v0[q]);
#pragma unroll
        for (int q = 0; q < 4; ++q) o[4 + q] = (short)f2bf(v1[q]);
        ((short8v*)dst)[i] = o;
    }
}

// ---------------------------------------------------------------------------
// C[m,n] = sum_k A[m,k]*Bt[n,k] + bias[n]; bf16 inputs, fp32 accum.
// 128x128 tile, BK=32, THREE-buffer counted-vmcnt pipeline (T4, proven in
// R6 attn): stage kk+2 each iter; barrier waits vmcnt(4) = only the OLDEST
// stage, the newer one stays in flight across the barrier -> each stage has
// ~2 compute phases (~450 cyc) to cover L2 latency.
//
// SWAPPED-OPERAND epilogue: acc = mfma(bf, af) -> lane holds 4 CONSECUTIVE
// n per m-row -> 8B (bf16) / 16B (fp32) vector stores. R6's 64x scalar-u16
// epilogue caused L2 read-for-ownership (+24MB FETCH) and 2x WRITE traffic.
// ---------------------------------------------------------------------------
__global__ __launch_bounds__(256) void gemm_bt_bias(
    const u16* __restrict__ A, const u16* __restrict__ Bt,
    const void* __restrict__ biasv, void* __restrict__ Cv,
    int M, int N, int K, const int* __restrict__ flagp, int out_flagged) {
    __shared__ __align__(16) u16 lA[3][128 * 32];
    __shared__ __align__(16) u16 lB[3][128 * 32];
    const int fl = flagp[0];
    const int fo = out_flagged ? fl : 1;  // 1 => bf16 output

    const int tid = threadIdx.x;
    const int w = __builtin_amdgcn_readfirstlane(tid >> 6);
    const int lane = tid & 63;
    const int quad = lane >> 4;
    const int l16 = lane & 15;
    const int bm = blockIdx.y * 128;
    const int bn = blockIdx.x * 128;
    const int wm = (w >> 1) * 64;
    const int wn = (w & 1) * 64;

    f32x4 acc[4][4];
#pragma unroll
    for (int i = 0; i < 4; ++i)
#pragma unroll
        for (int j = 0; j < 4; ++j) acc[i][j] = {0.f, 0.f, 0.f, 0.f};

    const int kiters = K >> 5;
    // stage tile kk into buf: chunk = w*2+c (1KB each), lane writes 16B
    // 4 vmem instructions per wave per stage (2 for A, 2 for B)
#define GEMM_STAGE(kk, buf)                                                            \
    {                                                                                  \
        _Pragma("unroll") for (int c = 0; c < 2; ++c) {                                \
            const int chunk = w * 2 + c;                                               \
            const int off = chunk * 1024 + lane * 16;                                  \
            const int m_ = off >> 6;                                                   \
            const int kb_ = off & 63;                                                  \
            gld_lds16((const char*)(A + (size_t)(bm + m_) * K + (kk) * 32) + kb_,      \
                      (char*)&lA[buf][0] + chunk * 1024);                              \
            gld_lds16((const char*)(Bt + (size_t)(bn + m_) * K + (kk) * 32) + kb_,     \
                      (char*)&lB[buf][0] + chunk * 1024);                              \
        }                                                                              \
    }

    GEMM_STAGE(0, 0);
    if (kiters > 1) GEMM_STAGE(1, 1);
    int cur = 0;
    for (int kk = 0; kk < kiters; ++kk) {
        // wait the OLDEST stage only (kk); stage kk+1 stays in flight
        if (kk + 1 < kiters) {
            asm volatile("s_waitcnt vmcnt(4)" ::: "memory");
        } else {
            asm volatile("s_waitcnt vmcnt(0)" ::: "memory");
        }
        __builtin_amdgcn_s_barrier();  // all waves' stage(kk) complete
        if (kk + 2 < kiters) {
            const int nb = (cur + 2 >= 3) ? cur - 1 : cur + 2;
            GEMM_STAGE(kk + 2, nb);
        }

        short8v af[4], bf[4];
#pragma unroll
        for (int t = 0; t < 4; ++t) {
            af[t] = *(const short8v*)&lA[cur][(wm + t * 16 + l16) * 32 + quad * 8];
            bf[t] = *(const short8v*)&lB[cur][(wn + t * 16 + l16) * 32 + quad * 8];
        }
        __builtin_amdgcn_s_setprio(1);
#pragma unroll
        for (int i = 0; i < 4; ++i)
#pragma unroll
            for (int j = 0; j < 4; ++j)
                acc[i][j] = __builtin_amdgcn_mfma_f32_16x16x32_bf16(bf[j], af[i], acc[i][j], 0, 0, 0);
        __builtin_amdgcn_s_setprio(0);
        cur = (cur == 2) ? 0 : cur + 1;
    }
#undef GEMM_STAGE

    // epilogue: acc[i][j] holds C[m = bm+wm+i*16+l16][n = bn+wn+j*16+quad*4+r]
    // -> 4 consecutive n per lane: 8B/16B vector stores, full-line coalescing
#pragma unroll
    for (int j = 0; j < 4; ++j) {
        const int n0 = bn + wn + j * 16 + quad * 4;
        float bv0, bv1, bv2, bv3;
        if (fl) {
            const u32x2 bw = *(const u32x2*)((const u16*)biasv + n0);
            bv0 = bf2f((u16)(bw.x & 0xffff));
            bv1 = bf2f((u16)(bw.x >> 16));
            bv2 = bf2f((u16)(bw.y & 0xffff));
            bv3 = bf2f((u16)(bw.y >> 16));
        } else {
            const f32x4 bw = *(const f32x4*)((const float*)biasv + n0);
            bv0 = bw[0]; bv1 = bw[1]; bv2 = bw[2]; bv3 = bw[3];
        }
#pragma unroll
        for (int i = 0; i < 4; ++i) {
            const size_t base = (size_t)(bm + wm + i * 16 + l16) * N + n0;
            const float v0 = acc[i][j][0] + bv0, v1 = acc[i][j][1] + bv1;
            const float v2 = acc[i][j][2] + bv2, v3 = acc[i][j][3] + bv3;
            if (fo) {
                u32x2 ov;
                ov.x = cvtpk(v0, v1);
                ov.y = cvtpk(v2, v3);
                *(u32x2*)((u16*)Cv + base) = ov;
            } else {
                f32x4 ov = {v0, v1, v2, v3};
                *(f32x4*)((float*)Cv + base) = ov;
            }
        }
    }
}

// ---------------------------------------------------------------------------
// Fused: RoPE on q,k + reorder to (B,H,S,64)  [blocks 0..8191]
//        V -> V^T (B,H,64,S) via padded LDS   [blocks 8192..9215]
// ---------------------------------------------------------------------------
__global__ __launch_bounds__(256) void rope_vt(
    const u16* __restrict__ qkv, u16* __restrict__ qws, u16* __restrict__ kws,
    u16* __restrict__ vTo) {
    __shared__ u16 tile[64 * 65];
    if (blockIdx.x < 8192) {
        const int idx = blockIdx.x * 256 + threadIdx.x;
        const int i = idx & 31;
        const int h = (idx >> 5) & 15;
        const int s = (idx >> 9) & 2047;
        const int b = idx >> 20;
        const u16* src = qkv + ((size_t)(b * S_LEN + s)) * (3 * DM) + h * HD + 2 * i;
        const u32 qp = *(const u32*)(src);
        const u32 kp = *(const u32*)(src + DM);
        const float q1 = bf2f((u16)qp), q2 = bf2f((u16)(qp >> 16));
        const float k1 = bf2f((u16)kp), k2 = bf2f((u16)(kp >> 16));
        const float freq = expf(-(float)(2 * i) * 0.14391156831212787f);
        const float th = (float)s * freq;
        float sn, cs;
        sincosf(th, &sn, &cs);
        const float oq1 = q1 * cs - q2 * sn, oq2 = q1 * sn + q2 * cs;
        const float ok1 = k1 * cs - k2 * sn, ok2 = k1 * sn + k2 * cs;
        const size_t dst = ((size_t)((b * NH + h) * S_LEN + s)) * HD + 2 * i;
        *(u32*)(qws + dst) = (u32)f2bf(oq1) | ((u32)f2bf(oq2) << 16);
        *(u32*)(kws + dst) = (u32)f2bf(ok1) | ((u32)f2bf(ok2) << 16);
    } else {
        const int bid = blockIdx.x - 8192;
        const int s0 = (bid & 31) * 64;
        const int h = (bid >> 5) & 15, b = bid >> 9;
        const int t = threadIdx.x;
#pragma unroll
        for (int it = 0; it < 16; ++it) {
            const int e = t + 256 * it;
            const int sl = e >> 6, d = e & 63;
            tile[sl * 65 + d] =
                qkv[((size_t)(b * S_LEN + s0 + sl)) * (3 * DM) + 2 * DM + h * HD + d];
        }
        __syncthreads();
#pragma unroll
        for (int it = 0; it < 16; ++it) {
            const int e = t + 256 * it;
            const int d = e >> 6, sl = e & 63;
            vTo[((size_t)((b * NH + h) * HD + d)) * S_LEN + s0 + sl] = tile[sl * 65 + d];
        }
    }
}

// ---------------------------------------------------------------------------
// Flash attention. 256-thread blocks = 4 waves x 16 q-rows (64 rows/block).
// Grid 1024: id = qbr*32 + g, g=(b,h) low 5 bits -> XCD pin; qb = 31-qbr.
// Counted-vmcnt K/V pipeline; swizzled LDS; cvt_pk epilogue. (R6-verified.)
// ---------------------------------------------------------------------------
__global__ __launch_bounds__(256, 4) void attn_kernel(
    const u16* __restrict__ qws, const u16* __restrict__ kws,
    const u16* __restrict__ vT, u16* __restrict__ ows) {
    __shared__ __align__(16) u16 kl[2][64 * 64];    // K dbuf, 16 KB
    __shared__ __align__(16) u16 vl[64 * 64];       // V single, 8 KB
    __shared__ __align__(16) u32 pl32[4][16 * 36];  // per-wave P, 9216 B
    const int t = threadIdx.x;
    const int w = __builtin_amdgcn_readfirstlane(t >> 6);
    const int lane = t & 63;
    const int quad = lane >> 4;
    const int l16 = lane & 15;

    const int id = blockIdx.x;
    const int g = id & 31;          // (b,h) -> XCD pin g%8
    const int qb = 31 - (id >> 5);  // longest-first
    const int h = g & 15, b = g >> 4;
    const int q0 = qb * 64 + w * 16;  // wave's 16 q-rows

    const size_t bh = (size_t)(b * NH + h);
    const u16* qbp = qws + bh * (size_t)S_LEN * HD;
    const u16* kb = kws + bh * (size_t)S_LEN * HD;
    const u16* vb = vT + bh * (size_t)HD * S_LEN;

    // staging geometry: wave w stages rows [w*8+s*32 .. +7], lane -> 16B
    const int r0 = lane >> 3;                // row within 8-row group
    const int srcc = (lane & 7) ^ r0;        // pre-swizzled col16
    const int xorb = (l16 & 7) << 4;         // read-side swizzle XOR

    short8v qf[2];
#pragma unroll
    for (int hf = 0; hf < 2; ++hf)
        qf[hf] = *(const short8v*)(qbp + (size_t)(q0 + l16) * HD + hf * 32 + quad * 8);

    f32x4 oaccT[4];  // row = d (quad*4+r), col = q (l16)
#pragma unroll
    for (int d = 0; d < 4; ++d) oaccT[d] = {0.f, 0.f, 0.f, 0.f};
    float mrow = -__builtin_inff();
    float lrow = 0.f;

    // prologue: stage K[0]
#pragma unroll
    for (int s = 0; s < 2; ++s) {
        const int row = w * 8 + s * 32 + r0;
        gld_lds16(kb + (size_t)row * HD + srcc * 8, (char*)&kl[0][0] + w * 1024 + s * 4096);
    }

    int cur = 0;
    for (int kt = 0; kt <= qb; ++kt) {
        __syncthreads();  // K[kt] staged by all; V free; kl[cur^1] free
        // issue V[kt] FIRST (oldest in vm queue), then K[kt+1]
#pragma unroll
        for (int s = 0; s < 2; ++s) {
            const int row = w * 8 + s * 32 + r0;
            gld_lds16(vb + (size_t)row * S_LEN + kt * 64 + srcc * 8,
                      (char*)&vl[0] + w * 1024 + s * 4096);
        }
        if (kt < qb) {
#pragma unroll
            for (int s = 0; s < 2; ++s) {
                const int row = w * 8 + s * 32 + r0;
                gld_lds16(kb + (size_t)((kt + 1) * 64 + row) * HD + srcc * 8,
                          (char*)&kl[cur ^ 1][0] + w * 1024 + s * 4096);
            }
        }
        const char* Kb = (const char*)&kl[cur][0];

        // S^T sub-tiles: row = k (quad*4+r within sub), col = q (l16)
        f32x4 s4[4];
        __builtin_amdgcn_s_setprio(1);
#pragma unroll
        for (int sub = 0; sub < 4; ++sub) {
            const int lin = (sub * 16 + l16) * 128 + quad * 16;
            const short8v k0 = *(const short8v*)(Kb + (lin ^ xorb));
            const short8v k1 = *(const short8v*)(Kb + ((lin + 64) ^ xorb));
            f32x4 a = {0.f, 0.f, 0.f, 0.f};
            a = __builtin_amdgcn_mfma_f32_16x16x32_bf16(k0, qf[0], a, 0, 0, 0);
            a = __builtin_amdgcn_mfma_f32_16x16x32_bf16(k1, qf[1], a, 0, 0, 0);
            s4[sub] = a;
        }
        __builtin_amdgcn_s_setprio(0);
        float sv[16];
#pragma unroll
        for (int sub = 0; sub < 4; ++sub)
#pragma unroll
            for (int r = 0; r < 4; ++r) sv[sub * 4 + r] = s4[sub][r] * 0.125f;
        if (kt == qb) {  // masked diagonal tile: k > q -> -inf
            const int qloc = w * 16 + l16;
#pragma unroll
            for (int sub = 0; sub < 4; ++sub)
#pragma unroll
                for (int r = 0; r < 4; ++r)
                    if (sub * 16 + quad * 4 + r > qloc) sv[sub * 4 + r] = -__builtin_inff();
        }
        // per-q-row max: 15 in-lane (tree) + 2 cross-lane
        float a0 = fmaxf(sv[0], sv[1]), a1 = fmaxf(sv[2], sv[3]);
        float a2 = fmaxf(sv[4], sv[5]), a3 = fmaxf(sv[6], sv[7]);
        float a4 = fmaxf(sv[8], sv[9]), a5 = fmaxf(sv[10], sv[11]);
        float a6 = fmaxf(sv[12], sv[13]), a7 = fmaxf(sv[14], sv[15]);
        a0 = fmaxf(a0, a1); a2 = fmaxf(a2, a3);
        a4 = fmaxf(a4, a5); a6 = fmaxf(a6, a7);
        a0 = fmaxf(a0, a2); a4 = fmaxf(a4, a6);
        float mx = fmaxf(a0, a4);
        mx = fmaxf(mx, __shfl_xor(mx, 16));
        mx = fmaxf(mx, __shfl_xor(mx, 32));
        const float mnew = fmaxf(mrow, mx);
        const float alpha = __expf(mrow - mnew);
        mrow = mnew;
        float p[16];
#pragma unroll
        for (int i = 0; i < 16; ++i) p[i] = __expf(sv[i] - mnew);
        float b0 = p[0] + p[1], b1 = p[2] + p[3], b2 = p[4] + p[5], b3 = p[6] + p[7];
        float b4 = p[8] + p[9], b5 = p[10] + p[11], b6 = p[12] + p[13], b7 = p[14] + p[15];
        b0 += b1; b2 += b3; b4 += b5; b6 += b7;
        b0 += b2; b4 += b6;
        float ps = b0 + b4;
        ps += __shfl_xor(ps, 16);
        ps += __shfl_xor(ps, 32);
        lrow = lrow * alpha + ps;
#pragma unroll
        for (int d = 0; d < 4; ++d) oaccT[d] *= alpha;
        // pack P[q=l16][k] via cvt_pk; 4x b64 writes (stride-36 rows)
        u32* prow = &pl32[w][l16 * 36];
#pragma unroll
        for (int sub = 0; sub < 4; ++sub) {
            u32x2 pw;
            pw.x = cvtpk(p[sub * 4 + 0], p[sub * 4 + 1]);
            pw.y = cvtpk(p[sub * 4 + 2], p[sub * 4 + 3]);
            *(u32x2*)&prow[sub * 8 + quad * 2] = pw;
        }
        asm volatile("s_waitcnt lgkmcnt(0)" ::: "memory");  // P visible (DS in-order)
        // wait own V chunks (K[kt+1] stays in flight), then join
        if (kt < qb) {
            asm volatile("s_waitcnt vmcnt(2)" ::: "memory");
        } else {
            asm volatile("s_waitcnt vmcnt(0)" ::: "memory");
        }
        __builtin_amdgcn_s_barrier();
        asm volatile("" ::: "memory");
        // PV: B-frag = P[q][c2*32 + quad*8 .. +7]; A-frag = V^T rows
        __builtin_amdgcn_s_setprio(1);
#pragma unroll
        for (int c2 = 0; c2 < 2; ++c2) {
            const short8v pf = *(const short8v*)&pl32[w][l16 * 36 + c2 * 16 + quad * 4];
#pragma unroll
            for (int d = 0; d < 4; ++d) {
                const int lin = (d * 16 + l16) * 128 + c2 * 64 + quad * 16;
                const short8v vfd = *(const short8v*)((const char*)&vl[0] + (lin ^ xorb));
                oaccT[d] = __builtin_amdgcn_mfma_f32_16x16x32_bf16(vfd, pf, oaccT[d], 0, 0, 0);
            }
        }
        __builtin_amdgcn_s_setprio(0);
        cur ^= 1;
    }

    // epilogue: O[q][d], q = q0+l16, d = df*16+quad*4+r -> 8B packed stores
    const float inv = 1.0f / lrow;
    const size_t rowbase = ((size_t)(b * S_LEN + q0 + l16)) * DM + h * HD;
#pragma unroll
    for (int df = 0; df < 4; ++df) {
        const int d0 = df * 16 + quad * 4;
        u32x2 ov;
        ov.x = cvtpk(oaccT[df][0] * inv, oaccT[df][1] * inv);
        ov.y = cvtpk(oaccT[df][2] * inv, oaccT[df][3] * inv);
        *(u32x2*)(ows + rowbase + d0) = ov;
    }
}

extern "C" void kernel_launch(void* const* d_in, const int* in_sizes, int n_in,
                              void* d_out, int out_size, void* d_ws, size_t ws_size,
                              hipStream_t stream) {
    const void* x = d_in[0];
    const void* w_qkv = d_in[1];
    const void* b_qkv = d_in[2];
    const void* w_out = d_in[3];
    const void* b_out = d_in[4];

    int* flag = (int*)d_ws;
    u16* qkv = (u16*)d_ws + 8;                      // 16B-aligned, 24 MB
    u16* qws = qkv + (size_t)TOK * 3 * DM;          // (B,H,S,64), 8 MB
    u16* kws = qws + (size_t)NB * NH * S_LEN * HD;  // 8 MB
    u16* vT = kws + (size_t)NB * NH * S_LEN * HD;   // (B,H,64,S), 8 MB
    u16* woutb = vT + (size_t)NB * NH * HD * S_LEN; // 2 MB
    u16* ows = qkv;    // alias: qkv dead after rope_vt
    u16* xb = qws;     // alias: xb dead before rope_vt writes qws
    u16* wqkvb = kws;  // alias: wqkvb dead before rope_vt writes kws

    detect_dtype<<<1, 256, 0, stream>>>((const u32*)x, flag);
    convert_all<<<(XCH + WQCH + WOCH) / 256, 256, 0, stream>>>(
        x, w_qkv, w_out, xb, wqkvb, woutb, flag);

    gemm_bt_bias<<<dim3(3 * DM / 128, TOK / 128), 256, 0, stream>>>(
        xb, wqkvb, b_qkv, qkv, TOK, 3 * DM, DM, flag, 0);
    rope_vt<<<8192 + 1024, 256, 0, stream>>>(qkv, qws, kws, vT);
    // 1-D grid: id = qbr*32 + g, g=(b,h). 1024 blocks x 256 threads.
    attn_kernel<<<dim3(32 * 32), 256, 0, stream>>>(qws, kws, vT, ows);
    gemm_bt_bias<<<dim3(DM / 128, TOK / 128), 256, 0, stream>>>(
        ows, woutb, b_out, d_out, TOK, DM, DM, flag, 1);
}